// Round 6
// baseline (391.395 us; speedup 1.0000x reference)
//
#include <hip/hip_runtime.h>

#define AS1 __attribute__((address_space(1)))
#define AS3 __attribute__((address_space(3)))

typedef _Float16 f16x8 __attribute__((ext_vector_type(8)));
typedef _Float16 f16x4 __attribute__((ext_vector_type(4)));
typedef _Float16 f16x2 __attribute__((ext_vector_type(2)));
typedef float f32x4 __attribute__((ext_vector_type(4)));

#define MFMA16(a, b, c) __builtin_amdgcn_mfma_f32_16x16x32_f16((a), (b), (c), 0, 0, 0)

// ---------------------------------------------------------------- helpers
__device__ __forceinline__ float silu_f(float v) { return v / (1.f + expf(-v)); }

__device__ __forceinline__ void gload_lds16(const void* g, void* l) {
    __builtin_amdgcn_global_load_lds((AS1 void*)g, (AS3 void*)l, 16, 0, 0);
}

// ---------------------------------------------------------------- f32 -> f16 convert
__global__ void cvt_f16(const float* __restrict__ in, _Float16* __restrict__ out, int n) {
    int i = (blockIdx.x * blockDim.x + threadIdx.x) * 4;
    if (i >= n) return;
    float4 v = *(const float4*)&in[i];
    f16x4 h = { (_Float16)v.x, (_Float16)v.y, (_Float16)v.z, (_Float16)v.w };
    *(f16x4*)&out[i] = h;
}

__global__ void zero_f32(float* __restrict__ p, int n) {
    int i = (blockIdx.x * blockDim.x + threadIdx.x) * 4;
    if (i >= n) return;
    float4 z = {0.f, 0.f, 0.f, 0.f};
    *(float4*)&p[i] = z;
}

// ---------------------------------------------------------------- split-K GEMM: C += A * B^T
// A: (M x K) f16, B: (N x K) f16, C: (M x N) f32 pre-zeroed; grid.z splits K.
// 768 blocks at the fused shape -> 3 blocks/CU so barrier drains overlap (m114).
__global__ __launch_bounds__(256) void gemm_bt_sk(const _Float16* __restrict__ A,
                                                  const _Float16* __restrict__ B,
                                                  float* __restrict__ C, int N, int K,
                                                  int KS) {
    __shared__ _Float16 As[128 * 32];
    __shared__ _Float16 Bs[128 * 32];
    const int tid = threadIdx.x;
    const int rowA0 = blockIdx.y * 128, rowB0 = blockIdx.x * 128;
    const int kOff = blockIdx.z * KS;
    const int lane = tid & 63;
    const int wave = tid >> 6;
    const int wr = (wave >> 1) * 64, wc = (wave & 1) * 64;
    const int fr = lane & 15, kof = (lane >> 4) * 8;
    const int sr0 = tid >> 2;
    const int sc0 = (tid & 3) * 8;

    f32x4 zero = {0.f, 0.f, 0.f, 0.f};
    f32x4 acc[4][4];
#pragma unroll
    for (int i = 0; i < 4; i++)
#pragma unroll
        for (int j = 0; j < 4; j++) acc[i][j] = zero;

    const _Float16* Abase = A + (long)(rowA0 + sr0) * K + sc0 + kOff;
    const _Float16* Bbase = B + (long)(rowB0 + sr0) * K + sc0 + kOff;
    const long chunk2 = (long)64 * K;

    for (int k0 = 0; k0 < KS; k0 += 32) {
        __syncthreads();
        gload_lds16(Abase + k0,          &As[tid * 8]);
        gload_lds16(Abase + k0 + chunk2, &As[2048 + tid * 8]);
        gload_lds16(Bbase + k0,          &Bs[tid * 8]);
        gload_lds16(Bbase + k0 + chunk2, &Bs[2048 + tid * 8]);
        __syncthreads();
        f16x8 af[4], bf[4];
#pragma unroll
        for (int mi = 0; mi < 4; mi++) af[mi] = *(const f16x8*)&As[(wr + mi * 16 + fr) * 32 + kof];
#pragma unroll
        for (int ni = 0; ni < 4; ni++) bf[ni] = *(const f16x8*)&Bs[(wc + ni * 16 + fr) * 32 + kof];
#pragma unroll
        for (int mi = 0; mi < 4; mi++)
#pragma unroll
            for (int ni = 0; ni < 4; ni++)
                acc[mi][ni] = MFMA16(af[mi], bf[ni], acc[mi][ni]);
    }
    const int rbase = (lane >> 4) * 4;
#pragma unroll
    for (int mi = 0; mi < 4; mi++)
#pragma unroll
        for (int ni = 0; ni < 4; ni++) {
            int row = rowA0 + wr + mi * 16 + rbase;
            int col = rowB0 + wc + ni * 16 + fr;
#pragma unroll
            for (int r = 0; r < 4; r++)
                unsafeAtomicAdd(&C[(long)(row + r) * N + col], acc[mi][ni][r]);
        }
}

// ---------------------------------------------------------------- beta / log-alpha projections
__global__ __launch_bounds__(256) void proj_ba(const float* __restrict__ x,
                                               const float* __restrict__ w_beta,
                                               const float* __restrict__ w_alpha,
                                               const float* __restrict__ log_A,
                                               const float* __restrict__ dt_bias,
                                               float* __restrict__ betaB,
                                               float* __restrict__ lalphaB) {
    __shared__ float xs[2048];
    const int s = blockIdx.x, tid = threadIdx.x;
    *(float4*)&xs[tid * 8]     = *(const float4*)&x[(long)s * 2048 + tid * 8];
    *(float4*)&xs[tid * 8 + 4] = *(const float4*)&x[(long)s * 2048 + tid * 8 + 4];
    __syncthreads();
    const int o = tid >> 3, j = tid & 7;
    const float* w = (o < 16) ? &w_beta[(long)o * 2048] : &w_alpha[(long)(o - 16) * 2048];
    float p = 0.f;
#pragma unroll 4
    for (int i = 0; i < 64; i++) {
        int d = i * 32 + j * 4;
        float4 wv = *(const float4*)&w[d];
        p += xs[d] * wv.x + xs[d + 1] * wv.y + xs[d + 2] * wv.z + xs[d + 3] * wv.w;
    }
    p += __shfl_xor(p, 1); p += __shfl_xor(p, 2); p += __shfl_xor(p, 4);
    if (j == 0) {
        if (o < 16) {
            betaB[s * 16 + o] = 1.f / (1.f + expf(-p));
        } else {
            int h = o - 16;
            float t = p + dt_bias[h];
            float sp = (t > 20.f) ? t : log1pf(expf(t));
            lalphaB[s * 16 + h] = -expf(log_A[h]) * sp;
        }
    }
}

// ---------------------------------------------------------------- fused causal conv(K=4)+SiLU+l2norm
// One block per token. Thread t owns channels [16t,16t+16). Waves 0/1 = q/k
// heads (l2-norm via 8-lane shfl groups), waves 2/3 = v (passthrough).
__global__ __launch_bounds__(256) void conv_norm(const float* __restrict__ pre,
                                                 const float* __restrict__ cw,
                                                 float* __restrict__ fqkv) {
    const int s = blockIdx.x, tid = threadIdx.x;
    const int c0 = tid * 16;
    const float* p0 = pre + (long)s * 6144 + c0;
    float v[16];
    float4 z4 = {0.f, 0.f, 0.f, 0.f};
#pragma unroll
    for (int g = 0; g < 4; ++g) {
        float4 r0 = *(const float4*)&p0[g * 4];
        float4 r1 = (s >= 1) ? *(const float4*)&p0[g * 4 - 6144]  : z4;
        float4 r2 = (s >= 2) ? *(const float4*)&p0[g * 4 - 12288] : z4;
        float4 r3 = (s >= 3) ? *(const float4*)&p0[g * 4 - 18432] : z4;
        const float* r0p = &r0.x; const float* r1p = &r1.x;
        const float* r2p = &r2.x; const float* r3p = &r3.x;
#pragma unroll
        for (int j = 0; j < 4; ++j) {
            float4 w = *(const float4*)&cw[(c0 + g * 4 + j) * 4];
            float a = r0p[j] * w.w + r1p[j] * w.z + r2p[j] * w.y + r3p[j] * w.x;
            v[g * 4 + j] = silu_f(a);
        }
    }
    const int sec = tid >> 6;  // 0=q wave, 1=k wave, 2/3=v waves
    if (sec < 2) {
        float ss = 0.f;
#pragma unroll
        for (int i = 0; i < 16; ++i) ss += v[i] * v[i];
        ss += __shfl_xor(ss, 1); ss += __shfl_xor(ss, 2); ss += __shfl_xor(ss, 4);
        float sc = rsqrtf(ss + 1e-6f);
        if (sec == 0) sc *= 0.08838834764831843f;  // 1/sqrt(128), queries only
#pragma unroll
        for (int i = 0; i < 16; ++i) v[i] *= sc;
    }
    float* dst = fqkv + (long)s * 4096 + c0;
#pragma unroll
    for (int g = 0; g < 4; ++g)
        *(float4*)&dst[g * 4] = *(float4*)&v[g * 4];
}

// ---------------------------------------------------------------- chunked delta rule: precompute
__global__ __launch_bounds__(256) void prep_chunk(const float* __restrict__ fqkv,
                                                  const float* __restrict__ betaB,
                                                  const float* __restrict__ lalphaB,
                                                  _Float16* __restrict__ Tw,
                                                  _Float16* __restrict__ Mw,
                                                  _Float16* __restrict__ QTw,
                                                  _Float16* __restrict__ KTw,
                                                  float* __restrict__ bgam,
                                                  float* __restrict__ gamC) {
    __shared__ _Float16 Kh[64 * 128];
    __shared__ _Float16 Qh[64 * 128];
    __shared__ float lg[64], bet[64];
    const int hc = blockIdx.x;
    const int h = hc >> 4, c = hc & 15, hq = h >> 1, s0 = c * 64;
    const int tid = threadIdx.x;
    if (tid < 64) {
        float la = lalphaB[(s0 + tid) * 16 + h];
#pragma unroll
        for (int d = 1; d < 64; d <<= 1) {
            float t = __shfl_up(la, d, 64);
            if (tid >= d) la += t;
        }
        lg[tid] = la;
        bet[tid] = betaB[(s0 + tid) * 16 + h];
    }
    for (int e = tid; e < 8192; e += 256) {
        int t = e >> 7, m = e & 127;
        Kh[e] = (_Float16)fqkv[(long)(s0 + t) * 4096 + 1024 + hq * 128 + m];
        Qh[e] = (_Float16)fqkv[(long)(s0 + t) * 4096 + hq * 128 + m];
    }
    __syncthreads();
    if (tid < 64) bgam[hc * 64 + tid] = bet[tid] * expf(lg[tid]);
    if (tid == 0) gamC[hc] = expf(lg[63]);
    for (int e = tid; e < 8192; e += 256) {
        int t = e >> 7;
        QTw[(long)hc * 8192 + e] = (_Float16)(expf(lg[t]) * (float)Qh[e]);
    }
    for (int e = tid; e < 8192; e += 256) {
        int m = e >> 6, t = e & 63;
        KTw[(long)hc * 8192 + e] = (_Float16)(expf(lg[63] - lg[t]) * (float)Kh[t * 128 + m]);
    }
    const int wv = tid >> 6, lane = tid & 63, fr = lane & 15, kof = (lane >> 4) * 8, quad = lane >> 4;
    f32x4 accT[4], accM[4];
    f32x4 zero = {0.f, 0.f, 0.f, 0.f};
#pragma unroll
    for (int ci = 0; ci < 4; ci++) { accT[ci] = zero; accM[ci] = zero; }
    for (int k0 = 0; k0 < 128; k0 += 32) {
        f16x8 ak = *(const f16x8*)&Kh[(wv * 16 + fr) * 128 + k0 + kof];
        f16x8 aq = *(const f16x8*)&Qh[(wv * 16 + fr) * 128 + k0 + kof];
#pragma unroll
        for (int ci = 0; ci < 4; ci++) {
            f16x8 bk = *(const f16x8*)&Kh[(ci * 16 + fr) * 128 + k0 + kof];
            accT[ci] = MFMA16(ak, bk, accT[ci]);
            accM[ci] = MFMA16(aq, bk, accM[ci]);
        }
    }
#pragma unroll
    for (int ci = 0; ci < 4; ci++)
#pragma unroll
        for (int r = 0; r < 4; r++) {
            int t = wv * 16 + quad * 4 + r, i = ci * 16 + fr;
            float e = expf(lg[t] - lg[i]);
            Tw[(long)hc * 4096 + t * 64 + i] = (_Float16)((i < t) ? bet[t] * e * accT[ci][r] : 0.f);
            Mw[(long)hc * 4096 + t * 64 + i] = (_Float16)((i <= t) ? e * accM[ci][r] : 0.f);
        }
}

// ---------------------------------------------------------------- blocked forward substitution
__global__ __launch_bounds__(128) void solve_chunk(const float* __restrict__ fqkv,
                                                   const float* __restrict__ betaB,
                                                   const float* __restrict__ bgam,
                                                   const _Float16* __restrict__ Tw,
                                                   _Float16* __restrict__ WTw,
                                                   _Float16* __restrict__ Bw,
                                                   _Float16* __restrict__ BTw) {
    __shared__ float Tl[64 * 64];
    __shared__ float XD[64 * 128];
    const int bid = blockIdx.x;
    const int hc = bid >> 1, half = bid & 1;
    const int h = hc >> 4, c = hc & 15, hq = h >> 1, s0 = c * 64;
    const int j = threadIdx.x;
    for (int e = j; e < 4096; e += 128) Tl[e] = (float)Tw[(long)hc * 4096 + e];
    __syncthreads();
    float Xa[16];
    for (int a = 0; a < 4; ++a) {
#pragma unroll
        for (int r = 0; r < 16; ++r) {
            int t = a * 16 + r;
            float rv;
            if (half == 0)
                rv = betaB[(s0 + t) * 16 + h] * fqkv[(long)(s0 + t) * 4096 + 2048 + h * 128 + j];
            else
                rv = bgam[hc * 64 + t] * fqkv[(long)(s0 + t) * 4096 + 1024 + hq * 128 + j];
            Xa[r] = rv;
        }
        for (int b = 0; b < a; ++b)
            for (int k = 0; k < 16; ++k) {
                float xk = XD[(b * 16 + k) * 128 + j];
#pragma unroll
                for (int r = 0; r < 16; ++r)
                    Xa[r] -= Tl[(a * 16 + r) * 64 + b * 16 + k] * xk;
            }
#pragma unroll
        for (int tp = 0; tp < 16; ++tp) {
            float xt = Xa[tp];
#pragma unroll
            for (int sp = 0; sp < 16; ++sp)
                if (sp > tp) Xa[sp] -= Tl[(a * 16 + sp) * 64 + a * 16 + tp] * xt;
        }
#pragma unroll
        for (int r = 0; r < 16; ++r) XD[(a * 16 + r) * 128 + j] = Xa[r];
    }
    __syncthreads();
    if (half == 0) {
        for (int t = 0; t < 64; ++t)
            WTw[((long)hc * 128 + j) * 64 + t] = (_Float16)XD[t * 128 + j];
    } else {
        for (int t = 0; t < 64; ++t) {
            _Float16 v = (_Float16)XD[t * 128 + j];
            Bw[(long)hc * 8192 + t * 128 + j] = v;
            BTw[((long)hc * 128 + j) * 64 + t] = v;
        }
    }
}

// ---------------------------------------------------------------- G = K~^T B (f16), Rt = (K~^T W)^T (f32)
__global__ __launch_bounds__(256) void gr_kernel(const _Float16* __restrict__ KTw,
                                                 const _Float16* __restrict__ BTw,
                                                 const _Float16* __restrict__ WTw,
                                                 _Float16* __restrict__ Gw,
                                                 float* __restrict__ Rtw) {
    __shared__ _Float16 KTl[128 * 72], BTl[128 * 72], WTl[128 * 72];
    const long hc = blockIdx.x;
    const int tid = threadIdx.x;
    {
        int r = tid >> 1, c0 = (tid & 1) * 32;
        const _Float16* k_ = &KTw[hc * 8192 + r * 64 + c0];
        const _Float16* b_ = &BTw[hc * 8192 + r * 64 + c0];
        const _Float16* w_ = &WTw[hc * 8192 + r * 64 + c0];
#pragma unroll
        for (int i = 0; i < 4; i++) {
            *(f16x8*)&KTl[r * 72 + c0 + i * 8] = *(const f16x8*)&k_[i * 8];
            *(f16x8*)&BTl[r * 72 + c0 + i * 8] = *(const f16x8*)&b_[i * 8];
            *(f16x8*)&WTl[r * 72 + c0 + i * 8] = *(const f16x8*)&w_[i * 8];
        }
    }
    __syncthreads();
    const int wv = tid >> 6, lane = tid & 63;
    const int fr = lane & 15, kof = (lane >> 4) * 8, quad = lane >> 4;
    f32x4 zero = {0.f, 0.f, 0.f, 0.f};
#pragma unroll
    for (int mi = 0; mi < 2; mi++) {
        int m0 = (wv * 2 + mi) * 16;
        f16x8 a0 = *(const f16x8*)&KTl[(m0 + fr) * 72 + kof];
        f16x8 a1 = *(const f16x8*)&KTl[(m0 + fr) * 72 + 32 + kof];
#pragma unroll
        for (int nj = 0; nj < 8; nj++) {
            f32x4 acc = zero;
            acc = MFMA16(a0, *(const f16x8*)&BTl[(nj * 16 + fr) * 72 + kof], acc);
            acc = MFMA16(a1, *(const f16x8*)&BTl[(nj * 16 + fr) * 72 + 32 + kof], acc);
#pragma unroll
            for (int r = 0; r < 4; r++)
                Gw[hc * 16384 + (long)(m0 + quad * 4 + r) * 128 + nj * 16 + fr] = (_Float16)acc[r];
        }
    }
#pragma unroll
    for (int ji = 0; ji < 2; ji++) {
        int j0 = (wv * 2 + ji) * 16;
        f16x8 a0 = *(const f16x8*)&WTl[(j0 + fr) * 72 + kof];
        f16x8 a1 = *(const f16x8*)&WTl[(j0 + fr) * 72 + 32 + kof];
#pragma unroll
        for (int nm = 0; nm < 8; nm++) {
            f32x4 acc = zero;
            acc = MFMA16(a0, *(const f16x8*)&KTl[(nm * 16 + fr) * 72 + kof], acc);
            acc = MFMA16(a1, *(const f16x8*)&KTl[(nm * 16 + fr) * 72 + 32 + kof], acc);
#pragma unroll
            for (int r = 0; r < 4; r++)
                Rtw[hc * 16384 + (long)(j0 + quad * 4 + r) * 128 + nm * 16 + fr] = acc[r];
        }
    }
}

// ---------------------------------------------------------------- serial affine state scan
__global__ __launch_bounds__(256) void serial_scan(const _Float16* __restrict__ Gw,
                                                   const float* __restrict__ Rtw,
                                                   const float* __restrict__ gamC,
                                                   float* __restrict__ Zdump) {
    __shared__ _Float16 Zhi[32 * 136], Zlo[32 * 136];
    __shared__ _Float16 Gl[128 * 136];
    const int tid = threadIdx.x;
    const int h = blockIdx.x >> 2, js = (blockIdx.x & 3) * 32;
    const int wv = tid >> 6, lane = tid & 63;
    const int fr = lane & 15, kof = (lane >> 4) * 8, quad = lane >> 4;
    const int gr_ = tid >> 1, gc_ = (tid & 1) * 64;

    for (int e = tid; e < 32 * 136; e += 256) { Zhi[e] = (_Float16)0.f; Zlo[e] = (_Float16)0.f; }
    float z[2][2][4];
#pragma unroll
    for (int jt = 0; jt < 2; jt++)
#pragma unroll
        for (int u = 0; u < 2; u++)
#pragma unroll
            for (int r = 0; r < 4; r++) z[jt][u][r] = 0.f;

    long hc0 = (long)h * 16;
    f16x8 gpre[8];
#pragma unroll
    for (int i = 0; i < 8; i++)
        gpre[i] = *(const f16x8*)&Gw[hc0 * 16384 + (long)gr_ * 128 + gc_ + i * 8];
    float rpre[2][2][4];
#pragma unroll
    for (int jt = 0; jt < 2; jt++)
#pragma unroll
        for (int u = 0; u < 2; u++)
#pragma unroll
            for (int r = 0; r < 4; r++)
                rpre[jt][u][r] = Rtw[hc0 * 16384 +
                                     (long)(js + jt * 16 + quad * 4 + r) * 128 +
                                     (2 * wv + u) * 16 + fr];
    __syncthreads();

    for (int c = 0; c < 16; ++c) {
        long hc = (long)h * 16 + c;
        float gC = gamC[hc];
#pragma unroll
        for (int i = 0; i < 8; i++)
            *(f16x8*)&Gl[gr_ * 136 + gc_ + i * 8] = gpre[i];
        long hcn = (long)h * 16 + (c < 15 ? c + 1 : 15);
        f16x8 gnext[8];
#pragma unroll
        for (int i = 0; i < 8; i++)
            gnext[i] = *(const f16x8*)&Gw[hcn * 16384 + (long)gr_ * 128 + gc_ + i * 8];
        float rnext[2][2][4];
#pragma unroll
        for (int jt = 0; jt < 2; jt++)
#pragma unroll
            for (int u = 0; u < 2; u++)
#pragma unroll
                for (int r = 0; r < 4; r++)
                    rnext[jt][u][r] = Rtw[hcn * 16384 +
                                          (long)(js + jt * 16 + quad * 4 + r) * 128 +
                                          (2 * wv + u) * 16 + fr];
        __syncthreads();
        f32x4 acc[2][2];
        f32x4 zero = {0.f, 0.f, 0.f, 0.f};
#pragma unroll
        for (int jt = 0; jt < 2; jt++)
#pragma unroll
            for (int u = 0; u < 2; u++) acc[jt][u] = zero;
        for (int k0 = 0; k0 < 128; k0 += 32) {
            f16x8 ahi[2], alo[2], bfr[2];
#pragma unroll
            for (int jt = 0; jt < 2; jt++) {
                ahi[jt] = *(const f16x8*)&Zhi[(jt * 16 + fr) * 136 + k0 + kof];
                alo[jt] = *(const f16x8*)&Zlo[(jt * 16 + fr) * 136 + k0 + kof];
            }
#pragma unroll
            for (int u = 0; u < 2; u++)
                bfr[u] = *(const f16x8*)&Gl[((2 * wv + u) * 16 + fr) * 136 + k0 + kof];
#pragma unroll
            for (int jt = 0; jt < 2; jt++)
#pragma unroll
                for (int u = 0; u < 2; u++) {
                    acc[jt][u] = MFMA16(ahi[jt], bfr[u], acc[jt][u]);
                    acc[jt][u] = MFMA16(alo[jt], bfr[u], acc[jt][u]);
                }
        }
        __syncthreads();
#pragma unroll
        for (int jt = 0; jt < 2; jt++)
#pragma unroll
            for (int u = 0; u < 2; u++)
#pragma unroll
                for (int r = 0; r < 4; r++) {
                    int j = jt * 16 + quad * 4 + r;
                    int m = (2 * wv + u) * 16 + fr;
                    Zdump[hc * 16384 + (long)(js + j) * 128 + m] = z[jt][u][r];
                    float zn = gC * z[jt][u][r] - acc[jt][u][r] + rpre[jt][u][r];
                    z[jt][u][r] = zn;
                    _Float16 hi = (_Float16)zn;
                    Zhi[j * 136 + m] = hi;
                    Zlo[j * 136 + m] = (_Float16)(zn - (float)hi);
                }
#pragma unroll
        for (int i = 0; i < 8; i++) gpre[i] = gnext[i];
#pragma unroll
        for (int jt = 0; jt < 2; jt++)
#pragma unroll
            for (int u = 0; u < 2; u++)
#pragma unroll
                for (int r = 0; r < 4; r++) rpre[jt][u][r] = rnext[jt][u][r];
    }
}

// ---------------------------------------------------------------- per-chunk output (parallel)
__global__ __launch_bounds__(256) void out_chunk(const float* __restrict__ Zdump,
                                                 const _Float16* __restrict__ Bw,
                                                 const _Float16* __restrict__ WTw,
                                                 const _Float16* __restrict__ QTw,
                                                 const _Float16* __restrict__ Mw,
                                                 float* __restrict__ ctx) {
    __shared__ _Float16 SThi[64 * 136], STlo[64 * 136], Bl[64 * 136];
    __shared__ _Float16 UT[64 * 72];
    const int bid = blockIdx.x;
    const long hc = bid >> 1;
    const int jh = (bid & 1) * 64;
    const int h = (int)(hc >> 4), c = (int)(hc & 15), s0 = c * 64;
    const int tid = threadIdx.x, wv = tid >> 6, lane = tid & 63;
    const int fr = lane & 15, kof = (lane >> 4) * 8, quad = lane >> 4;
    {
        int r = tid >> 2, c0 = (tid & 3) * 32;
        const float* src = &Zdump[hc * 16384 + (long)(jh + r) * 128 + c0];
#pragma unroll
        for (int i = 0; i < 8; i++) {
            float4 v = *(const float4*)&src[i * 4];
            _Float16 h0 = (_Float16)v.x, h1 = (_Float16)v.y, h2 = (_Float16)v.z, h3 = (_Float16)v.w;
            f16x4 hi = {h0, h1, h2, h3};
            f16x4 lo = {(_Float16)(v.x - (float)h0), (_Float16)(v.y - (float)h1),
                        (_Float16)(v.z - (float)h2), (_Float16)(v.w - (float)h3)};
            *(f16x4*)&SThi[r * 136 + c0 + i * 4] = hi;
            *(f16x4*)&STlo[r * 136 + c0 + i * 4] = lo;
        }
        const _Float16* bsrc = &Bw[hc * 8192 + r * 128 + c0];
#pragma unroll
        for (int i = 0; i < 4; i++)
            *(f16x8*)&Bl[r * 136 + c0 + i * 8] = *(const f16x8*)&bsrc[i * 8];
    }
    __syncthreads();
    const int t0 = wv * 16;
    f16x8 ba[4];
#pragma unroll
    for (int k = 0; k < 4; k++)
        ba[k] = *(const f16x8*)&Bl[(t0 + fr) * 136 + k * 32 + kof];
#pragma unroll
    for (int jt = 0; jt < 4; jt++) {
        f32x4 acc = {0.f, 0.f, 0.f, 0.f};
#pragma unroll
        for (int k = 0; k < 4; k++) {
            acc = MFMA16(ba[k], *(const f16x8*)&SThi[(jt * 16 + fr) * 136 + k * 32 + kof], acc);
            acc = MFMA16(ba[k], *(const f16x8*)&STlo[(jt * 16 + fr) * 136 + k * 32 + kof], acc);
        }
#pragma unroll
        for (int r = 0; r < 4; r++) {
            int t = t0 + quad * 4 + r;
            int j = jt * 16 + fr;
            float w = (float)WTw[hc * 8192 + (long)(jh + j) * 64 + t];
            UT[j * 72 + t] = (_Float16)(w - acc[r]);
        }
    }
    __syncthreads();
    f16x8 qa[4], ma[2];
#pragma unroll
    for (int k = 0; k < 4; k++)
        qa[k] = *(const f16x8*)&QTw[hc * 8192 + (long)(t0 + fr) * 128 + k * 32 + kof];
#pragma unroll
    for (int k = 0; k < 2; k++)
        ma[k] = *(const f16x8*)&Mw[hc * 4096 + (long)(t0 + fr) * 64 + k * 32 + kof];
#pragma unroll
    for (int jt = 0; jt < 4; jt++) {
        f32x4 acc = {0.f, 0.f, 0.f, 0.f};
#pragma unroll
        for (int k = 0; k < 4; k++) {
            acc = MFMA16(qa[k], *(const f16x8*)&SThi[(jt * 16 + fr) * 136 + k * 32 + kof], acc);
            acc = MFMA16(qa[k], *(const f16x8*)&STlo[(jt * 16 + fr) * 136 + k * 32 + kof], acc);
        }
#pragma unroll
        for (int k = 0; k < 2; k++)
            acc = MFMA16(ma[k], *(const f16x8*)&UT[(jt * 16 + fr) * 72 + k * 32 + kof], acc);
#pragma unroll
        for (int r = 0; r < 4; r++) {
            int t = t0 + quad * 4 + r;
            int j = jt * 16 + fr;
            ctx[(long)(s0 + t) * 2048 + h * 128 + jh + j] = acc[r];
        }
    }
}

// ---------------------------------------------------------------- rms_norm(ctx)*rms_w * silu(gate) -> f16
__global__ void epilogue_k(const float* __restrict__ ctx, const float* __restrict__ pre,
                           const float* __restrict__ rms_w, _Float16* __restrict__ y) {
    int gw = (blockIdx.x * blockDim.x + threadIdx.x) >> 6;
    int lane = threadIdx.x & 63;
    int s = gw >> 4, h = gw & 15;
    long base = (long)s * 2048 + h * 128;
    long gbase = (long)s * 6144 + 4096 + h * 128;
    float2 cv = *(const float2*)&ctx[base + lane * 2];
    float ss = cv.x * cv.x + cv.y * cv.y;
#pragma unroll
    for (int m = 1; m < 64; m <<= 1) ss += __shfl_xor(ss, m);
    float sc = rsqrtf(ss * (1.f / 128.f) + 1e-6f);
    int d = lane * 2;
    float2 rw = *(const float2*)&rms_w[d];
    float g0 = silu_f(pre[gbase + d]);
    float g1 = silu_f(pre[gbase + d + 1]);
    f16x2 hv = { (_Float16)(cv.x * sc * rw.x * g0), (_Float16)(cv.y * sc * rw.y * g1) };
    *(f16x2*)&y[base + d] = hv;
}

// ---------------------------------------------------------------- launch
extern "C" void kernel_launch(void* const* d_in, const int* in_sizes, int n_in,
                              void* d_out, int out_size, void* d_ws, size_t ws_size,
                              hipStream_t stream) {
    const float* x       = (const float*)d_in[0];
    const float* w_qkv   = (const float*)d_in[1];
    const float* w_gate  = (const float*)d_in[2];
    const float* w_beta  = (const float*)d_in[3];
    const float* w_alpha = (const float*)d_in[4];
    const float* log_A   = (const float*)d_in[5];
    const float* dt_bias = (const float*)d_in[6];
    const float* conv_w  = (const float*)d_in[7];
    const float* rms_w   = (const float*)d_in[8];
    const float* w_out   = (const float*)d_in[9];
    float* outp = (float*)d_out;

    char* ws = (char*)d_ws;
    size_t off = 0;
    _Float16* xb     = (_Float16*)(ws + off); off += (size_t)1024 * 2048 * 2;
    _Float16* wfused = (_Float16*)(ws + off); off += (size_t)6144 * 2048 * 2;
    _Float16* woutb  = (_Float16*)(ws + off); off += (size_t)2048 * 2048 * 2;
    _Float16* yb     = (_Float16*)(ws + off); off += (size_t)1024 * 2048 * 2;
    float* pre       = (float*)(ws + off);    off += (size_t)1024 * 6144 * 4;
    float* fqkv      = (float*)(ws + off);    off += (size_t)1024 * 4096 * 4;
    float* ctx       = (float*)(ws + off);    off += (size_t)1024 * 16 * 128 * 4;
    float* betaB     = (float*)(ws + off);    off += (size_t)1024 * 16 * 4;
    float* lalphaB   = (float*)(ws + off);    off += (size_t)1024 * 16 * 4;
    _Float16* Tw     = (_Float16*)(ws + off); off += (size_t)256 * 4096 * 2;
    _Float16* Mw     = (_Float16*)(ws + off); off += (size_t)256 * 4096 * 2;
    _Float16* QTw    = (_Float16*)(ws + off); off += (size_t)256 * 8192 * 2;
    _Float16* KTw    = (_Float16*)(ws + off); off += (size_t)256 * 8192 * 2;
    _Float16* WTw    = (_Float16*)(ws + off); off += (size_t)256 * 8192 * 2;
    _Float16* Bw     = (_Float16*)(ws + off); off += (size_t)256 * 8192 * 2;
    _Float16* BTw    = (_Float16*)(ws + off); off += (size_t)256 * 8192 * 2;
    float* bgam      = (float*)(ws + off);    off += (size_t)256 * 64 * 4;
    float* gamC      = (float*)(ws + off);    off += (size_t)256 * 4;
    _Float16* Gw     = (_Float16*)(ws + off); off += (size_t)256 * 16384 * 2;
    float* Rtw       = (float*)(ws + off);    off += (size_t)256 * 16384 * 4;
    // Zdump aliases fqkv: fqkv's last reader is solve_chunk; serial_scan
    // (producer of Zdump) runs strictly after it on the same stream.
    float* Zdump     = fqkv;

    cvt_f16<<<2048, 256, 0, stream>>>(x, xb, 1024 * 2048);
    cvt_f16<<<8192, 256, 0, stream>>>(w_qkv, wfused, 4096 * 2048);
    cvt_f16<<<4096, 256, 0, stream>>>(w_gate, wfused + (size_t)4096 * 2048, 2048 * 2048);
    cvt_f16<<<4096, 256, 0, stream>>>(w_out, woutb, 2048 * 2048);
    zero_f32<<<6144, 256, 0, stream>>>(pre, 1024 * 6144);

    // fused qkv+gate projection, split-K=2 -> 768 blocks (3/CU)
    gemm_bt_sk<<<dim3(48, 8, 2), 256, 0, stream>>>(xb, wfused, pre, 6144, 2048, 1024);
    proj_ba<<<1024, 256, 0, stream>>>(x, w_beta, w_alpha, log_A, dt_bias, betaB, lalphaB);
    conv_norm<<<1024, 256, 0, stream>>>(pre, conv_w, fqkv);

    prep_chunk<<<256, 256, 0, stream>>>(fqkv, betaB, lalphaB, Tw, Mw, QTw, KTw, bgam, gamC);
    solve_chunk<<<512, 128, 0, stream>>>(fqkv, betaB, bgam, Tw, WTw, Bw, BTw);
    gr_kernel<<<256, 256, 0, stream>>>(KTw, BTw, WTw, Gw, Rtw);
    serial_scan<<<64, 256, 0, stream>>>(Gw, Rtw, gamC, Zdump);
    out_chunk<<<512, 256, 0, stream>>>(Zdump, Bw, WTw, QTw, Mw, ctx);

    epilogue_k<<<4096, 256, 0, stream>>>(ctx, pre, rms_w, yb);
    zero_f32<<<2048, 256, 0, stream>>>(outp, 1024 * 2048);
    gemm_bt_sk<<<dim3(16, 8, 2), 256, 0, stream>>>(yb, woutb, outp, 2048, 2048, 1024);
}

// Round 7
// 363.691 us; speedup vs baseline: 1.0762x; 1.0762x over previous
//
#include <hip/hip_runtime.h>

#define AS1 __attribute__((address_space(1)))
#define AS3 __attribute__((address_space(3)))

typedef _Float16 f16x8 __attribute__((ext_vector_type(8)));
typedef _Float16 f16x4 __attribute__((ext_vector_type(4)));
typedef _Float16 f16x2 __attribute__((ext_vector_type(2)));
typedef float f32x4 __attribute__((ext_vector_type(4)));

#define MFMA16(a, b, c) __builtin_amdgcn_mfma_f32_16x16x32_f16((a), (b), (c), 0, 0, 0)

// ---------------------------------------------------------------- helpers
__device__ __forceinline__ float silu_f(float v) { return v / (1.f + expf(-v)); }

__device__ __forceinline__ void gload_lds16(const void* g, void* l) {
    __builtin_amdgcn_global_load_lds((AS1 void*)g, (AS3 void*)l, 16, 0, 0);
}

// ---------------------------------------------------------------- f32 -> f16 convert
__global__ void cvt_f16(const float* __restrict__ in, _Float16* __restrict__ out, int n) {
    int i = (blockIdx.x * blockDim.x + threadIdx.x) * 4;
    if (i >= n) return;
    float4 v = *(const float4*)&in[i];
    f16x4 h = { (_Float16)v.x, (_Float16)v.y, (_Float16)v.z, (_Float16)v.w };
    *(f16x4*)&out[i] = h;
}

// ---------------------------------------------------------------- GEMM: C = A * B^T, 64x128 tile
// A: (M x K) f16, B: (N x K) f16, C: (M x N) f32. Grid (N/128, M/64).
// 64-row tiles give 768 blocks (3/CU, even) at the fused shape -> no tail,
// multi-block barrier overlap (m114); plain stores, no atomics.
__global__ __launch_bounds__(256) void gemm_bt64(const _Float16* __restrict__ A,
                                                 const _Float16* __restrict__ B,
                                                 float* __restrict__ C, int N, int K) {
    __shared__ _Float16 S[192 * 32];   // rows 0..63 = A-tile, 64..191 = B-tile
    const int tid = threadIdx.x;
    const int rowA0 = blockIdx.y * 64, rowB0 = blockIdx.x * 128;
    const int lane = tid & 63;
    const int wv = tid >> 6;
    const int rw = (wv & 1) * 32, cw = (wv >> 1) * 64;
    const int fr = lane & 15, kof = (lane >> 4) * 8;

    // staging: 3 x 16B units per thread; unit u = tid + 256*i -> row u>>2, col (u&3)*8
    const _Float16* gp[3];
#pragma unroll
    for (int i = 0; i < 3; i++) {
        int u = tid + 256 * i;
        int row = u >> 2, c0 = (u & 3) * 8;
        gp[i] = (row < 64) ? A + (long)(rowA0 + row) * K + c0
                           : B + (long)(rowB0 + row - 64) * K + c0;
    }

    f32x4 zero = {0.f, 0.f, 0.f, 0.f};
    f32x4 acc[2][4];
#pragma unroll
    for (int mi = 0; mi < 2; mi++)
#pragma unroll
        for (int ni = 0; ni < 4; ni++) acc[mi][ni] = zero;

    for (int k0 = 0; k0 < K; k0 += 32) {
        __syncthreads();
#pragma unroll
        for (int i = 0; i < 3; i++)
            gload_lds16(gp[i] + k0, &S[(tid + 256 * i) * 8]);
        __syncthreads();
        f16x8 af[2], bf[4];
#pragma unroll
        for (int mi = 0; mi < 2; mi++) af[mi] = *(const f16x8*)&S[(rw + mi * 16 + fr) * 32 + kof];
#pragma unroll
        for (int ni = 0; ni < 4; ni++) bf[ni] = *(const f16x8*)&S[(64 + cw + ni * 16 + fr) * 32 + kof];
#pragma unroll
        for (int mi = 0; mi < 2; mi++)
#pragma unroll
            for (int ni = 0; ni < 4; ni++)
                acc[mi][ni] = MFMA16(af[mi], bf[ni], acc[mi][ni]);
    }
    const int rbase = (lane >> 4) * 4;
#pragma unroll
    for (int mi = 0; mi < 2; mi++)
#pragma unroll
        for (int ni = 0; ni < 4; ni++) {
            int row = rowA0 + rw + mi * 16 + rbase;
            int col = rowB0 + cw + ni * 16 + fr;
#pragma unroll
            for (int r = 0; r < 4; r++)
                C[(long)(row + r) * N + col] = acc[mi][ni][r];
        }
}

// ---------------------------------------------------------------- beta / log-alpha projections
__global__ __launch_bounds__(256) void proj_ba(const float* __restrict__ x,
                                               const float* __restrict__ w_beta,
                                               const float* __restrict__ w_alpha,
                                               const float* __restrict__ log_A,
                                               const float* __restrict__ dt_bias,
                                               float* __restrict__ betaB,
                                               float* __restrict__ lalphaB) {
    __shared__ float xs[2048];
    const int s = blockIdx.x, tid = threadIdx.x;
    *(float4*)&xs[tid * 8]     = *(const float4*)&x[(long)s * 2048 + tid * 8];
    *(float4*)&xs[tid * 8 + 4] = *(const float4*)&x[(long)s * 2048 + tid * 8 + 4];
    __syncthreads();
    const int o = tid >> 3, j = tid & 7;
    const float* w = (o < 16) ? &w_beta[(long)o * 2048] : &w_alpha[(long)(o - 16) * 2048];
    float p = 0.f;
#pragma unroll 4
    for (int i = 0; i < 64; i++) {
        int d = i * 32 + j * 4;
        float4 wv = *(const float4*)&w[d];
        p += xs[d] * wv.x + xs[d + 1] * wv.y + xs[d + 2] * wv.z + xs[d + 3] * wv.w;
    }
    p += __shfl_xor(p, 1); p += __shfl_xor(p, 2); p += __shfl_xor(p, 4);
    if (j == 0) {
        if (o < 16) {
            betaB[s * 16 + o] = 1.f / (1.f + expf(-p));
        } else {
            int h = o - 16;
            float t = p + dt_bias[h];
            float sp = (t > 20.f) ? t : log1pf(expf(t));
            lalphaB[s * 16 + h] = -expf(log_A[h]) * sp;
        }
    }
}

// ---------------------------------------------------------------- fused causal conv(K=4)+SiLU+l2norm
__global__ __launch_bounds__(256) void conv_norm(const float* __restrict__ pre,
                                                 const float* __restrict__ cw,
                                                 float* __restrict__ fqkv) {
    const int s = blockIdx.x, tid = threadIdx.x;
    const int c0 = tid * 16;
    const float* p0 = pre + (long)s * 6144 + c0;
    float v[16];
    float4 z4 = {0.f, 0.f, 0.f, 0.f};
#pragma unroll
    for (int g = 0; g < 4; ++g) {
        float4 r0 = *(const float4*)&p0[g * 4];
        float4 r1 = (s >= 1) ? *(const float4*)&p0[g * 4 - 6144]  : z4;
        float4 r2 = (s >= 2) ? *(const float4*)&p0[g * 4 - 12288] : z4;
        float4 r3 = (s >= 3) ? *(const float4*)&p0[g * 4 - 18432] : z4;
        const float* r0p = &r0.x; const float* r1p = &r1.x;
        const float* r2p = &r2.x; const float* r3p = &r3.x;
#pragma unroll
        for (int j = 0; j < 4; ++j) {
            float4 w = *(const float4*)&cw[(c0 + g * 4 + j) * 4];
            float a = r0p[j] * w.w + r1p[j] * w.z + r2p[j] * w.y + r3p[j] * w.x;
            v[g * 4 + j] = silu_f(a);
        }
    }
    const int sec = tid >> 6;  // 0=q wave, 1=k wave, 2/3=v waves
    if (sec < 2) {
        float ss = 0.f;
#pragma unroll
        for (int i = 0; i < 16; ++i) ss += v[i] * v[i];
        ss += __shfl_xor(ss, 1); ss += __shfl_xor(ss, 2); ss += __shfl_xor(ss, 4);
        float sc = rsqrtf(ss + 1e-6f);
        if (sec == 0) sc *= 0.08838834764831843f;  // 1/sqrt(128), queries only
#pragma unroll
        for (int i = 0; i < 16; ++i) v[i] *= sc;
    }
    float* dst = fqkv + (long)s * 4096 + c0;
#pragma unroll
    for (int g = 0; g < 4; ++g)
        *(float4*)&dst[g * 4] = *(float4*)&v[g * 4];
}

// ---------------------------------------------------------------- chunked delta rule: precompute
__global__ __launch_bounds__(256) void prep_chunk(const float* __restrict__ fqkv,
                                                  const float* __restrict__ betaB,
                                                  const float* __restrict__ lalphaB,
                                                  _Float16* __restrict__ Tw,
                                                  _Float16* __restrict__ Mw,
                                                  _Float16* __restrict__ QTw,
                                                  _Float16* __restrict__ KTw,
                                                  float* __restrict__ bgam,
                                                  float* __restrict__ gamC) {
    __shared__ _Float16 Kh[64 * 128];
    __shared__ _Float16 Qh[64 * 128];
    __shared__ float lg[64], bet[64];
    const int hc = blockIdx.x;
    const int h = hc >> 4, c = hc & 15, hq = h >> 1, s0 = c * 64;
    const int tid = threadIdx.x;
    if (tid < 64) {
        float la = lalphaB[(s0 + tid) * 16 + h];
#pragma unroll
        for (int d = 1; d < 64; d <<= 1) {
            float t = __shfl_up(la, d, 64);
            if (tid >= d) la += t;
        }
        lg[tid] = la;
        bet[tid] = betaB[(s0 + tid) * 16 + h];
    }
    for (int e = tid; e < 8192; e += 256) {
        int t = e >> 7, m = e & 127;
        Kh[e] = (_Float16)fqkv[(long)(s0 + t) * 4096 + 1024 + hq * 128 + m];
        Qh[e] = (_Float16)fqkv[(long)(s0 + t) * 4096 + hq * 128 + m];
    }
    __syncthreads();
    if (tid < 64) bgam[hc * 64 + tid] = bet[tid] * expf(lg[tid]);
    if (tid == 0) gamC[hc] = expf(lg[63]);
    for (int e = tid; e < 8192; e += 256) {
        int t = e >> 7;
        QTw[(long)hc * 8192 + e] = (_Float16)(expf(lg[t]) * (float)Qh[e]);
    }
    for (int e = tid; e < 8192; e += 256) {
        int m = e >> 6, t = e & 63;
        KTw[(long)hc * 8192 + e] = (_Float16)(expf(lg[63] - lg[t]) * (float)Kh[t * 128 + m]);
    }
    const int wv = tid >> 6, lane = tid & 63, fr = lane & 15, kof = (lane >> 4) * 8, quad = lane >> 4;
    f32x4 accT[4], accM[4];
    f32x4 zero = {0.f, 0.f, 0.f, 0.f};
#pragma unroll
    for (int ci = 0; ci < 4; ci++) { accT[ci] = zero; accM[ci] = zero; }
    for (int k0 = 0; k0 < 128; k0 += 32) {
        f16x8 ak = *(const f16x8*)&Kh[(wv * 16 + fr) * 128 + k0 + kof];
        f16x8 aq = *(const f16x8*)&Qh[(wv * 16 + fr) * 128 + k0 + kof];
#pragma unroll
        for (int ci = 0; ci < 4; ci++) {
            f16x8 bk = *(const f16x8*)&Kh[(ci * 16 + fr) * 128 + k0 + kof];
            accT[ci] = MFMA16(ak, bk, accT[ci]);
            accM[ci] = MFMA16(aq, bk, accM[ci]);
        }
    }
#pragma unroll
    for (int ci = 0; ci < 4; ci++)
#pragma unroll
        for (int r = 0; r < 4; r++) {
            int t = wv * 16 + quad * 4 + r, i = ci * 16 + fr;
            float e = expf(lg[t] - lg[i]);
            Tw[(long)hc * 4096 + t * 64 + i] = (_Float16)((i < t) ? bet[t] * e * accT[ci][r] : 0.f);
            Mw[(long)hc * 4096 + t * 64 + i] = (_Float16)((i <= t) ? e * accM[ci][r] : 0.f);
        }
}

// ---------------------------------------------------------------- blocked forward substitution
__global__ __launch_bounds__(128) void solve_chunk(const float* __restrict__ fqkv,
                                                   const float* __restrict__ betaB,
                                                   const float* __restrict__ bgam,
                                                   const _Float16* __restrict__ Tw,
                                                   _Float16* __restrict__ WTw,
                                                   _Float16* __restrict__ Bw,
                                                   _Float16* __restrict__ BTw) {
    __shared__ float Tl[64 * 64];
    __shared__ float XD[64 * 128];
    const int bid = blockIdx.x;
    const int hc = bid >> 1, half = bid & 1;
    const int h = hc >> 4, c = hc & 15, hq = h >> 1, s0 = c * 64;
    const int j = threadIdx.x;
    for (int e = j; e < 4096; e += 128) Tl[e] = (float)Tw[(long)hc * 4096 + e];
    __syncthreads();
    float Xa[16];
    for (int a = 0; a < 4; ++a) {
#pragma unroll
        for (int r = 0; r < 16; ++r) {
            int t = a * 16 + r;
            float rv;
            if (half == 0)
                rv = betaB[(s0 + t) * 16 + h] * fqkv[(long)(s0 + t) * 4096 + 2048 + h * 128 + j];
            else
                rv = bgam[hc * 64 + t] * fqkv[(long)(s0 + t) * 4096 + 1024 + hq * 128 + j];
            Xa[r] = rv;
        }
        for (int b = 0; b < a; ++b)
            for (int k = 0; k < 16; ++k) {
                float xk = XD[(b * 16 + k) * 128 + j];
#pragma unroll
                for (int r = 0; r < 16; ++r)
                    Xa[r] -= Tl[(a * 16 + r) * 64 + b * 16 + k] * xk;
            }
#pragma unroll
        for (int tp = 0; tp < 16; ++tp) {
            float xt = Xa[tp];
#pragma unroll
            for (int sp = 0; sp < 16; ++sp)
                if (sp > tp) Xa[sp] -= Tl[(a * 16 + sp) * 64 + a * 16 + tp] * xt;
        }
#pragma unroll
        for (int r = 0; r < 16; ++r) XD[(a * 16 + r) * 128 + j] = Xa[r];
    }
    __syncthreads();
    if (half == 0) {
        for (int t = 0; t < 64; ++t)
            WTw[((long)hc * 128 + j) * 64 + t] = (_Float16)XD[t * 128 + j];
    } else {
        for (int t = 0; t < 64; ++t) {
            _Float16 v = (_Float16)XD[t * 128 + j];
            Bw[(long)hc * 8192 + t * 128 + j] = v;
            BTw[((long)hc * 128 + j) * 64 + t] = v;
        }
    }
}

// ---------------------------------------------------------------- G = K~^T B (f16), Rt = (K~^T W)^T (f32)
__global__ __launch_bounds__(256) void gr_kernel(const _Float16* __restrict__ KTw,
                                                 const _Float16* __restrict__ BTw,
                                                 const _Float16* __restrict__ WTw,
                                                 _Float16* __restrict__ Gw,
                                                 float* __restrict__ Rtw) {
    __shared__ _Float16 KTl[128 * 72], BTl[128 * 72], WTl[128 * 72];
    const long hc = blockIdx.x;
    const int tid = threadIdx.x;
    {
        int r = tid >> 1, c0 = (tid & 1) * 32;
        const _Float16* k_ = &KTw[hc * 8192 + r * 64 + c0];
        const _Float16* b_ = &BTw[hc * 8192 + r * 64 + c0];
        const _Float16* w_ = &WTw[hc * 8192 + r * 64 + c0];
#pragma unroll
        for (int i = 0; i < 4; i++) {
            *(f16x8*)&KTl[r * 72 + c0 + i * 8] = *(const f16x8*)&k_[i * 8];
            *(f16x8*)&BTl[r * 72 + c0 + i * 8] = *(const f16x8*)&b_[i * 8];
            *(f16x8*)&WTl[r * 72 + c0 + i * 8] = *(const f16x8*)&w_[i * 8];
        }
    }
    __syncthreads();
    const int wv = tid >> 6, lane = tid & 63;
    const int fr = lane & 15, kof = (lane >> 4) * 8, quad = lane >> 4;
    f32x4 zero = {0.f, 0.f, 0.f, 0.f};
#pragma unroll
    for (int mi = 0; mi < 2; mi++) {
        int m0 = (wv * 2 + mi) * 16;
        f16x8 a0 = *(const f16x8*)&KTl[(m0 + fr) * 72 + kof];
        f16x8 a1 = *(const f16x8*)&KTl[(m0 + fr) * 72 + 32 + kof];
#pragma unroll
        for (int nj = 0; nj < 8; nj++) {
            f32x4 acc = zero;
            acc = MFMA16(a0, *(const f16x8*)&BTl[(nj * 16 + fr) * 72 + kof], acc);
            acc = MFMA16(a1, *(const f16x8*)&BTl[(nj * 16 + fr) * 72 + 32 + kof], acc);
#pragma unroll
            for (int r = 0; r < 4; r++)
                Gw[hc * 16384 + (long)(m0 + quad * 4 + r) * 128 + nj * 16 + fr] = (_Float16)acc[r];
        }
    }
#pragma unroll
    for (int ji = 0; ji < 2; ji++) {
        int j0 = (wv * 2 + ji) * 16;
        f16x8 a0 = *(const f16x8*)&WTl[(j0 + fr) * 72 + kof];
        f16x8 a1 = *(const f16x8*)&WTl[(j0 + fr) * 72 + 32 + kof];
#pragma unroll
        for (int nm = 0; nm < 8; nm++) {
            f32x4 acc = zero;
            acc = MFMA16(a0, *(const f16x8*)&KTl[(nm * 16 + fr) * 72 + kof], acc);
            acc = MFMA16(a1, *(const f16x8*)&KTl[(nm * 16 + fr) * 72 + 32 + kof], acc);
#pragma unroll
            for (int r = 0; r < 4; r++)
                Rtw[hc * 16384 + (long)(j0 + quad * 4 + r) * 128 + nm * 16 + fr] = acc[r];
        }
    }
}

// ---------------------------------------------------------------- serial affine state scan
__global__ __launch_bounds__(256) void serial_scan(const _Float16* __restrict__ Gw,
                                                   const float* __restrict__ Rtw,
                                                   const float* __restrict__ gamC,
                                                   float* __restrict__ Zdump) {
    __shared__ _Float16 Zhi[32 * 136], Zlo[32 * 136];
    __shared__ _Float16 Gl[128 * 136];
    const int tid = threadIdx.x;
    const int h = blockIdx.x >> 2, js = (blockIdx.x & 3) * 32;
    const int wv = tid >> 6, lane = tid & 63;
    const int fr = lane & 15, kof = (lane >> 4) * 8, quad = lane >> 4;
    const int gr_ = tid >> 1, gc_ = (tid & 1) * 64;

    for (int e = tid; e < 32 * 136; e += 256) { Zhi[e] = (_Float16)0.f; Zlo[e] = (_Float16)0.f; }
    float z[2][2][4];
#pragma unroll
    for (int jt = 0; jt < 2; jt++)
#pragma unroll
        for (int u = 0; u < 2; u++)
#pragma unroll
            for (int r = 0; r < 4; r++) z[jt][u][r] = 0.f;

    long hc0 = (long)h * 16;
    f16x8 gpre[8];
#pragma unroll
    for (int i = 0; i < 8; i++)
        gpre[i] = *(const f16x8*)&Gw[hc0 * 16384 + (long)gr_ * 128 + gc_ + i * 8];
    float rpre[2][2][4];
#pragma unroll
    for (int jt = 0; jt < 2; jt++)
#pragma unroll
        for (int u = 0; u < 2; u++)
#pragma unroll
            for (int r = 0; r < 4; r++)
                rpre[jt][u][r] = Rtw[hc0 * 16384 +
                                     (long)(js + jt * 16 + quad * 4 + r) * 128 +
                                     (2 * wv + u) * 16 + fr];
    __syncthreads();

    for (int c = 0; c < 16; ++c) {
        long hc = (long)h * 16 + c;
        float gC = gamC[hc];
#pragma unroll
        for (int i = 0; i < 8; i++)
            *(f16x8*)&Gl[gr_ * 136 + gc_ + i * 8] = gpre[i];
        long hcn = (long)h * 16 + (c < 15 ? c + 1 : 15);
        f16x8 gnext[8];
#pragma unroll
        for (int i = 0; i < 8; i++)
            gnext[i] = *(const f16x8*)&Gw[hcn * 16384 + (long)gr_ * 128 + gc_ + i * 8];
        float rnext[2][2][4];
#pragma unroll
        for (int jt = 0; jt < 2; jt++)
#pragma unroll
            for (int u = 0; u < 2; u++)
#pragma unroll
                for (int r = 0; r < 4; r++)
                    rnext[jt][u][r] = Rtw[hcn * 16384 +
                                          (long)(js + jt * 16 + quad * 4 + r) * 128 +
                                          (2 * wv + u) * 16 + fr];
        __syncthreads();
        f32x4 acc[2][2];
        f32x4 zero = {0.f, 0.f, 0.f, 0.f};
#pragma unroll
        for (int jt = 0; jt < 2; jt++)
#pragma unroll
            for (int u = 0; u < 2; u++) acc[jt][u] = zero;
        for (int k0 = 0; k0 < 128; k0 += 32) {
            f16x8 ahi[2], alo[2], bfr[2];
#pragma unroll
            for (int jt = 0; jt < 2; jt++) {
                ahi[jt] = *(const f16x8*)&Zhi[(jt * 16 + fr) * 136 + k0 + kof];
                alo[jt] = *(const f16x8*)&Zlo[(jt * 16 + fr) * 136 + k0 + kof];
            }
#pragma unroll
            for (int u = 0; u < 2; u++)
                bfr[u] = *(const f16x8*)&Gl[((2 * wv + u) * 16 + fr) * 136 + k0 + kof];
#pragma unroll
            for (int jt = 0; jt < 2; jt++)
#pragma unroll
                for (int u = 0; u < 2; u++) {
                    acc[jt][u] = MFMA16(ahi[jt], bfr[u], acc[jt][u]);
                    acc[jt][u] = MFMA16(alo[jt], bfr[u], acc[jt][u]);
                }
        }
        __syncthreads();
#pragma unroll
        for (int jt = 0; jt < 2; jt++)
#pragma unroll
            for (int u = 0; u < 2; u++)
#pragma unroll
                for (int r = 0; r < 4; r++) {
                    int j = jt * 16 + quad * 4 + r;
                    int m = (2 * wv + u) * 16 + fr;
                    Zdump[hc * 16384 + (long)(js + j) * 128 + m] = z[jt][u][r];
                    float zn = gC * z[jt][u][r] - acc[jt][u][r] + rpre[jt][u][r];
                    z[jt][u][r] = zn;
                    _Float16 hi = (_Float16)zn;
                    Zhi[j * 136 + m] = hi;
                    Zlo[j * 136 + m] = (_Float16)(zn - (float)hi);
                }
#pragma unroll
        for (int i = 0; i < 8; i++) gpre[i] = gnext[i];
#pragma unroll
        for (int jt = 0; jt < 2; jt++)
#pragma unroll
            for (int u = 0; u < 2; u++)
#pragma unroll
                for (int r = 0; r < 4; r++) rpre[jt][u][r] = rnext[jt][u][r];
    }
}

// ---------------------------------------------------------------- per-chunk output (parallel)
__global__ __launch_bounds__(256) void out_chunk(const float* __restrict__ Zdump,
                                                 const _Float16* __restrict__ Bw,
                                                 const _Float16* __restrict__ WTw,
                                                 const _Float16* __restrict__ QTw,
                                                 const _Float16* __restrict__ Mw,
                                                 float* __restrict__ ctx) {
    __shared__ _Float16 SThi[64 * 136], STlo[64 * 136], Bl[64 * 136];
    __shared__ _Float16 UT[64 * 72];
    const int bid = blockIdx.x;
    const long hc = bid >> 1;
    const int jh = (bid & 1) * 64;
    const int h = (int)(hc >> 4), c = (int)(hc & 15), s0 = c * 64;
    const int tid = threadIdx.x, wv = tid >> 6, lane = tid & 63;
    const int fr = lane & 15, kof = (lane >> 4) * 8, quad = lane >> 4;
    {
        int r = tid >> 2, c0 = (tid & 3) * 32;
        const float* src = &Zdump[hc * 16384 + (long)(jh + r) * 128 + c0];
#pragma unroll
        for (int i = 0; i < 8; i++) {
            float4 v = *(const float4*)&src[i * 4];
            _Float16 h0 = (_Float16)v.x, h1 = (_Float16)v.y, h2 = (_Float16)v.z, h3 = (_Float16)v.w;
            f16x4 hi = {h0, h1, h2, h3};
            f16x4 lo = {(_Float16)(v.x - (float)h0), (_Float16)(v.y - (float)h1),
                        (_Float16)(v.z - (float)h2), (_Float16)(v.w - (float)h3)};
            *(f16x4*)&SThi[r * 136 + c0 + i * 4] = hi;
            *(f16x4*)&STlo[r * 136 + c0 + i * 4] = lo;
        }
        const _Float16* bsrc = &Bw[hc * 8192 + r * 128 + c0];
#pragma unroll
        for (int i = 0; i < 4; i++)
            *(f16x8*)&Bl[r * 136 + c0 + i * 8] = *(const f16x8*)&bsrc[i * 8];
    }
    __syncthreads();
    const int t0 = wv * 16;
    f16x8 ba[4];
#pragma unroll
    for (int k = 0; k < 4; k++)
        ba[k] = *(const f16x8*)&Bl[(t0 + fr) * 136 + k * 32 + kof];
#pragma unroll
    for (int jt = 0; jt < 4; jt++) {
        f32x4 acc = {0.f, 0.f, 0.f, 0.f};
#pragma unroll
        for (int k = 0; k < 4; k++) {
            acc = MFMA16(ba[k], *(const f16x8*)&SThi[(jt * 16 + fr) * 136 + k * 32 + kof], acc);
            acc = MFMA16(ba[k], *(const f16x8*)&STlo[(jt * 16 + fr) * 136 + k * 32 + kof], acc);
        }
#pragma unroll
        for (int r = 0; r < 4; r++) {
            int t = t0 + quad * 4 + r;
            int j = jt * 16 + fr;
            float w = (float)WTw[hc * 8192 + (long)(jh + j) * 64 + t];
            UT[j * 72 + t] = (_Float16)(w - acc[r]);
        }
    }
    __syncthreads();
    f16x8 qa[4], ma[2];
#pragma unroll
    for (int k = 0; k < 4; k++)
        qa[k] = *(const f16x8*)&QTw[hc * 8192 + (long)(t0 + fr) * 128 + k * 32 + kof];
#pragma unroll
    for (int k = 0; k < 2; k++)
        ma[k] = *(const f16x8*)&Mw[hc * 4096 + (long)(t0 + fr) * 64 + k * 32 + kof];
#pragma unroll
    for (int jt = 0; jt < 4; jt++) {
        f32x4 acc = {0.f, 0.f, 0.f, 0.f};
#pragma unroll
        for (int k = 0; k < 4; k++) {
            acc = MFMA16(qa[k], *(const f16x8*)&SThi[(jt * 16 + fr) * 136 + k * 32 + kof], acc);
            acc = MFMA16(qa[k], *(const f16x8*)&STlo[(jt * 16 + fr) * 136 + k * 32 + kof], acc);
        }
#pragma unroll
        for (int k = 0; k < 2; k++)
            acc = MFMA16(ma[k], *(const f16x8*)&UT[(jt * 16 + fr) * 72 + k * 32 + kof], acc);
#pragma unroll
        for (int r = 0; r < 4; r++) {
            int t = t0 + quad * 4 + r;
            int j = jt * 16 + fr;
            ctx[(long)(s0 + t) * 2048 + h * 128 + jh + j] = acc[r];
        }
    }
}

// ---------------------------------------------------------------- rms_norm(ctx)*rms_w * silu(gate) -> f16
__global__ void epilogue_k(const float* __restrict__ ctx, const float* __restrict__ pre,
                           const float* __restrict__ rms_w, _Float16* __restrict__ y) {
    int gw = (blockIdx.x * blockDim.x + threadIdx.x) >> 6;
    int lane = threadIdx.x & 63;
    int s = gw >> 4, h = gw & 15;
    long base = (long)s * 2048 + h * 128;
    long gbase = (long)s * 6144 + 4096 + h * 128;
    float2 cv = *(const float2*)&ctx[base + lane * 2];
    float ss = cv.x * cv.x + cv.y * cv.y;
#pragma unroll
    for (int m = 1; m < 64; m <<= 1) ss += __shfl_xor(ss, m);
    float sc = rsqrtf(ss * (1.f / 128.f) + 1e-6f);
    int d = lane * 2;
    float2 rw = *(const float2*)&rms_w[d];
    float g0 = silu_f(pre[gbase + d]);
    float g1 = silu_f(pre[gbase + d + 1]);
    f16x2 hv = { (_Float16)(cv.x * sc * rw.x * g0), (_Float16)(cv.y * sc * rw.y * g1) };
    *(f16x2*)&y[base + d] = hv;
}

// ---------------------------------------------------------------- launch
extern "C" void kernel_launch(void* const* d_in, const int* in_sizes, int n_in,
                              void* d_out, int out_size, void* d_ws, size_t ws_size,
                              hipStream_t stream) {
    const float* x       = (const float*)d_in[0];
    const float* w_qkv   = (const float*)d_in[1];
    const float* w_gate  = (const float*)d_in[2];
    const float* w_beta  = (const float*)d_in[3];
    const float* w_alpha = (const float*)d_in[4];
    const float* log_A   = (const float*)d_in[5];
    const float* dt_bias = (const float*)d_in[6];
    const float* conv_w  = (const float*)d_in[7];
    const float* rms_w   = (const float*)d_in[8];
    const float* w_out   = (const float*)d_in[9];
    float* outp = (float*)d_out;

    char* ws = (char*)d_ws;
    size_t off = 0;
    _Float16* xb     = (_Float16*)(ws + off); off += (size_t)1024 * 2048 * 2;
    _Float16* wfused = (_Float16*)(ws + off); off += (size_t)6144 * 2048 * 2;
    _Float16* woutb  = (_Float16*)(ws + off); off += (size_t)2048 * 2048 * 2;
    _Float16* yb     = (_Float16*)(ws + off); off += (size_t)1024 * 2048 * 2;
    float* pre       = (float*)(ws + off);    off += (size_t)1024 * 6144 * 4;
    float* fqkv      = (float*)(ws + off);    off += (size_t)1024 * 4096 * 4;
    float* ctx       = (float*)(ws + off);    off += (size_t)1024 * 16 * 128 * 4;
    float* betaB     = (float*)(ws + off);    off += (size_t)1024 * 16 * 4;
    float* lalphaB   = (float*)(ws + off);    off += (size_t)1024 * 16 * 4;
    _Float16* Tw     = (_Float16*)(ws + off); off += (size_t)256 * 4096 * 2;
    _Float16* Mw     = (_Float16*)(ws + off); off += (size_t)256 * 4096 * 2;
    _Float16* QTw    = (_Float16*)(ws + off); off += (size_t)256 * 8192 * 2;
    _Float16* KTw    = (_Float16*)(ws + off); off += (size_t)256 * 8192 * 2;
    _Float16* WTw    = (_Float16*)(ws + off); off += (size_t)256 * 8192 * 2;
    _Float16* Bw     = (_Float16*)(ws + off); off += (size_t)256 * 8192 * 2;
    _Float16* BTw    = (_Float16*)(ws + off); off += (size_t)256 * 8192 * 2;
    float* bgam      = (float*)(ws + off);    off += (size_t)256 * 64 * 4;
    float* gamC      = (float*)(ws + off);    off += (size_t)256 * 4;
    _Float16* Gw     = (_Float16*)(ws + off); off += (size_t)256 * 16384 * 2;
    float* Rtw       = (float*)(ws + off);    off += (size_t)256 * 16384 * 4;
    // Zdump aliases fqkv: fqkv's last reader is solve_chunk; serial_scan
    // (producer of Zdump) runs strictly after it on the same stream.
    float* Zdump     = fqkv;

    cvt_f16<<<2048, 256, 0, stream>>>(x, xb, 1024 * 2048);
    cvt_f16<<<8192, 256, 0, stream>>>(w_qkv, wfused, 4096 * 2048);
    cvt_f16<<<4096, 256, 0, stream>>>(w_gate, wfused + (size_t)4096 * 2048, 2048 * 2048);
    cvt_f16<<<4096, 256, 0, stream>>>(w_out, woutb, 2048 * 2048);

    // fused qkv+gate projection: 64x128 tiles -> 768 blocks (3/CU even), plain stores
    gemm_bt64<<<dim3(48, 16), 256, 0, stream>>>(xb, wfused, pre, 6144, 2048);
    proj_ba<<<1024, 256, 0, stream>>>(x, w_beta, w_alpha, log_A, dt_bias, betaB, lalphaB);
    conv_norm<<<1024, 256, 0, stream>>>(pre, conv_w, fqkv);

    prep_chunk<<<256, 256, 0, stream>>>(fqkv, betaB, lalphaB, Tw, Mw, QTw, KTw, bgam, gamC);
    solve_chunk<<<512, 128, 0, stream>>>(fqkv, betaB, bgam, Tw, WTw, Bw, BTw);
    gr_kernel<<<256, 256, 0, stream>>>(KTw, BTw, WTw, Gw, Rtw);
    serial_scan<<<64, 256, 0, stream>>>(Gw, Rtw, gamC, Zdump);
    out_chunk<<<512, 256, 0, stream>>>(Zdump, Bw, WTw, QTw, Mw, ctx);

    epilogue_k<<<4096, 256, 0, stream>>>(ctx, pre, rms_w, yb);
    // out projection: 64x128 tiles -> 256 blocks (1/CU even), plain stores
    gemm_bt64<<<dim3(16, 16), 256, 0, stream>>>(yb, woutb, outp, 2048, 2048);
}

// Round 8
// 338.381 us; speedup vs baseline: 1.1567x; 1.0748x over previous
//
#include <hip/hip_runtime.h>

#define AS1 __attribute__((address_space(1)))
#define AS3 __attribute__((address_space(3)))

typedef _Float16 f16x8 __attribute__((ext_vector_type(8)));
typedef _Float16 f16x4 __attribute__((ext_vector_type(4)));
typedef _Float16 f16x2 __attribute__((ext_vector_type(2)));
typedef float f32x4 __attribute__((ext_vector_type(4)));

#define MFMA16(a, b, c) __builtin_amdgcn_mfma_f32_16x16x32_f16((a), (b), (c), 0, 0, 0)

// ---------------------------------------------------------------- helpers
__device__ __forceinline__ float silu_f(float v) { return v / (1.f + expf(-v)); }

__device__ __forceinline__ void gload_lds16(const void* g, void* l) {
    __builtin_amdgcn_global_load_lds((AS1 void*)g, (AS3 void*)l, 16, 0, 0);
}

// ---------------------------------------------------------------- fused cvt (x,w_qkv,w_gate,w_out -> one f16 region) + proj_ba
// blocks [0,18432): convert 18,874,368 f32 -> f16 (dst = xb|wfused|woutb contiguous)
// blocks [18432,19456): beta/log-alpha projections (independent of cvt; overlaps)
__global__ __launch_bounds__(256) void cvt_proj(const float* __restrict__ x,
                                                const float* __restrict__ w_qkv,
                                                const float* __restrict__ w_gate,
                                                const float* __restrict__ w_out,
                                                _Float16* __restrict__ dst,
                                                const float* __restrict__ w_beta,
                                                const float* __restrict__ w_alpha,
                                                const float* __restrict__ log_A,
                                                const float* __restrict__ dt_bias,
                                                float* __restrict__ betaB,
                                                float* __restrict__ lalphaB) {
    __shared__ float xs[2048];
    const int bid = blockIdx.x, tid = threadIdx.x;
    if (bid < 18432) {
        long i = ((long)bid * 256 + tid) * 4;
        const float* src; long off;
        if (i < 2097152)       { src = x;      off = 0; }
        else if (i < 10485760) { src = w_qkv;  off = 2097152; }
        else if (i < 14680064) { src = w_gate; off = 10485760; }
        else                   { src = w_out;  off = 14680064; }
        float4 v = *(const float4*)&src[i - off];
        f16x4 h = { (_Float16)v.x, (_Float16)v.y, (_Float16)v.z, (_Float16)v.w };
        *(f16x4*)&dst[i] = h;
        return;
    }
    const int s = bid - 18432;
    *(float4*)&xs[tid * 8]     = *(const float4*)&x[(long)s * 2048 + tid * 8];
    *(float4*)&xs[tid * 8 + 4] = *(const float4*)&x[(long)s * 2048 + tid * 8 + 4];
    __syncthreads();
    const int o = tid >> 3, j = tid & 7;
    const float* w = (o < 16) ? &w_beta[(long)o * 2048] : &w_alpha[(long)(o - 16) * 2048];
    float p = 0.f;
#pragma unroll 4
    for (int i = 0; i < 64; i++) {
        int d = i * 32 + j * 4;
        float4 wv = *(const float4*)&w[d];
        p += xs[d] * wv.x + xs[d + 1] * wv.y + xs[d + 2] * wv.z + xs[d + 3] * wv.w;
    }
    p += __shfl_xor(p, 1); p += __shfl_xor(p, 2); p += __shfl_xor(p, 4);
    if (j == 0) {
        if (o < 16) {
            betaB[s * 16 + o] = 1.f / (1.f + expf(-p));
        } else {
            int h = o - 16;
            float t = p + dt_bias[h];
            float sp = (t > 20.f) ? t : log1pf(expf(t));
            lalphaB[s * 16 + h] = -expf(log_A[h]) * sp;
        }
    }
}

// ---------------------------------------------------------------- GEMM: C(f16) = A * B^T, 64x128 tile
__global__ __launch_bounds__(256) void gemm_bt64h(const _Float16* __restrict__ A,
                                                  const _Float16* __restrict__ B,
                                                  _Float16* __restrict__ C, int N, int K) {
    __shared__ _Float16 S[192 * 32];
    const int tid = threadIdx.x;
    const int rowA0 = blockIdx.y * 64, rowB0 = blockIdx.x * 128;
    const int lane = tid & 63;
    const int wv = tid >> 6;
    const int rw = (wv & 1) * 32, cw = (wv >> 1) * 64;
    const int fr = lane & 15, kof = (lane >> 4) * 8;

    const _Float16* gp[3];
#pragma unroll
    for (int i = 0; i < 3; i++) {
        int u = tid + 256 * i;
        int row = u >> 2, c0 = (u & 3) * 8;
        gp[i] = (row < 64) ? A + (long)(rowA0 + row) * K + c0
                           : B + (long)(rowB0 + row - 64) * K + c0;
    }

    f32x4 zero = {0.f, 0.f, 0.f, 0.f};
    f32x4 acc[2][4];
#pragma unroll
    for (int mi = 0; mi < 2; mi++)
#pragma unroll
        for (int ni = 0; ni < 4; ni++) acc[mi][ni] = zero;

    for (int k0 = 0; k0 < K; k0 += 32) {
        __syncthreads();
#pragma unroll
        for (int i = 0; i < 3; i++)
            gload_lds16(gp[i] + k0, &S[(tid + 256 * i) * 8]);
        __syncthreads();
        f16x8 af[2], bf[4];
#pragma unroll
        for (int mi = 0; mi < 2; mi++) af[mi] = *(const f16x8*)&S[(rw + mi * 16 + fr) * 32 + kof];
#pragma unroll
        for (int ni = 0; ni < 4; ni++) bf[ni] = *(const f16x8*)&S[(64 + cw + ni * 16 + fr) * 32 + kof];
#pragma unroll
        for (int mi = 0; mi < 2; mi++)
#pragma unroll
            for (int ni = 0; ni < 4; ni++)
                acc[mi][ni] = MFMA16(af[mi], bf[ni], acc[mi][ni]);
    }
    const int rbase = (lane >> 4) * 4;
#pragma unroll
    for (int mi = 0; mi < 2; mi++)
#pragma unroll
        for (int ni = 0; ni < 4; ni++) {
            int row = rowA0 + rw + mi * 16 + rbase;
            int col = rowB0 + cw + ni * 16 + fr;
#pragma unroll
            for (int r = 0; r < 4; r++)
                C[(long)(row + r) * N + col] = (_Float16)acc[mi][ni][r];
        }
}

// ---------------------------------------------------------------- GEMM: C(f32) = A * B^T, 64x128 tile
__global__ __launch_bounds__(256) void gemm_bt64(const _Float16* __restrict__ A,
                                                 const _Float16* __restrict__ B,
                                                 float* __restrict__ C, int N, int K) {
    __shared__ _Float16 S[192 * 32];
    const int tid = threadIdx.x;
    const int rowA0 = blockIdx.y * 64, rowB0 = blockIdx.x * 128;
    const int lane = tid & 63;
    const int wv = tid >> 6;
    const int rw = (wv & 1) * 32, cw = (wv >> 1) * 64;
    const int fr = lane & 15, kof = (lane >> 4) * 8;

    const _Float16* gp[3];
#pragma unroll
    for (int i = 0; i < 3; i++) {
        int u = tid + 256 * i;
        int row = u >> 2, c0 = (u & 3) * 8;
        gp[i] = (row < 64) ? A + (long)(rowA0 + row) * K + c0
                           : B + (long)(rowB0 + row - 64) * K + c0;
    }

    f32x4 zero = {0.f, 0.f, 0.f, 0.f};
    f32x4 acc[2][4];
#pragma unroll
    for (int mi = 0; mi < 2; mi++)
#pragma unroll
        for (int ni = 0; ni < 4; ni++) acc[mi][ni] = zero;

    for (int k0 = 0; k0 < K; k0 += 32) {
        __syncthreads();
#pragma unroll
        for (int i = 0; i < 3; i++)
            gload_lds16(gp[i] + k0, &S[(tid + 256 * i) * 8]);
        __syncthreads();
        f16x8 af[2], bf[4];
#pragma unroll
        for (int mi = 0; mi < 2; mi++) af[mi] = *(const f16x8*)&S[(rw + mi * 16 + fr) * 32 + kof];
#pragma unroll
        for (int ni = 0; ni < 4; ni++) bf[ni] = *(const f16x8*)&S[(64 + cw + ni * 16 + fr) * 32 + kof];
#pragma unroll
        for (int mi = 0; mi < 2; mi++)
#pragma unroll
            for (int ni = 0; ni < 4; ni++)
                acc[mi][ni] = MFMA16(af[mi], bf[ni], acc[mi][ni]);
    }
    const int rbase = (lane >> 4) * 4;
#pragma unroll
    for (int mi = 0; mi < 2; mi++)
#pragma unroll
        for (int ni = 0; ni < 4; ni++) {
            int row = rowA0 + rw + mi * 16 + rbase;
            int col = rowB0 + cw + ni * 16 + fr;
#pragma unroll
            for (int r = 0; r < 4; r++)
                C[(long)(row + r) * N + col] = acc[mi][ni][r];
        }
}

// ---------------------------------------------------------------- fused causal conv(K=4)+SiLU+l2norm (f16 pre)
__global__ __launch_bounds__(256) void conv_norm(const _Float16* __restrict__ pre,
                                                 const float* __restrict__ cw,
                                                 float* __restrict__ fqkv) {
    const int s = blockIdx.x, tid = threadIdx.x;
    const int c0 = tid * 16;
    const _Float16* p0 = pre + (long)s * 6144 + c0;
    float v[16];
#pragma unroll
    for (int g = 0; g < 4; ++g) {
        f16x4 r0 = *(const f16x4*)&p0[g * 4];
        f16x4 r1 = {}, r2 = {}, r3 = {};
        if (s >= 1) r1 = *(const f16x4*)&p0[g * 4 - 6144];
        if (s >= 2) r2 = *(const f16x4*)&p0[g * 4 - 12288];
        if (s >= 3) r3 = *(const f16x4*)&p0[g * 4 - 18432];
#pragma unroll
        for (int j = 0; j < 4; ++j) {
            float4 w = *(const float4*)&cw[(c0 + g * 4 + j) * 4];
            float a = (float)r0[j] * w.w + (float)r1[j] * w.z +
                      (float)r2[j] * w.y + (float)r3[j] * w.x;
            v[g * 4 + j] = silu_f(a);
        }
    }
    const int sec = tid >> 6;  // 0=q wave, 1=k wave, 2/3=v waves
    if (sec < 2) {
        float ss = 0.f;
#pragma unroll
        for (int i = 0; i < 16; ++i) ss += v[i] * v[i];
        ss += __shfl_xor(ss, 1); ss += __shfl_xor(ss, 2); ss += __shfl_xor(ss, 4);
        float sc = rsqrtf(ss + 1e-6f);
        if (sec == 0) sc *= 0.08838834764831843f;  // 1/sqrt(128), queries only
#pragma unroll
        for (int i = 0; i < 16; ++i) v[i] *= sc;
    }
    float* dst = fqkv + (long)s * 4096 + c0;
#pragma unroll
    for (int g = 0; g < 4; ++g)
        *(float4*)&dst[g * 4] = *(float4*)&v[g * 4];
}

// ---------------------------------------------------------------- chunked delta rule: precompute
__global__ __launch_bounds__(256) void prep_chunk(const float* __restrict__ fqkv,
                                                  const float* __restrict__ betaB,
                                                  const float* __restrict__ lalphaB,
                                                  _Float16* __restrict__ Tw,
                                                  _Float16* __restrict__ Mw,
                                                  _Float16* __restrict__ QTw,
                                                  _Float16* __restrict__ KTw,
                                                  float* __restrict__ bgam,
                                                  float* __restrict__ gamC) {
    __shared__ _Float16 Kh[64 * 128];
    __shared__ _Float16 Qh[64 * 128];
    __shared__ float lg[64], bet[64];
    const int hc = blockIdx.x;
    const int h = hc >> 4, c = hc & 15, hq = h >> 1, s0 = c * 64;
    const int tid = threadIdx.x;
    if (tid < 64) {
        float la = lalphaB[(s0 + tid) * 16 + h];
#pragma unroll
        for (int d = 1; d < 64; d <<= 1) {
            float t = __shfl_up(la, d, 64);
            if (tid >= d) la += t;
        }
        lg[tid] = la;
        bet[tid] = betaB[(s0 + tid) * 16 + h];
    }
    for (int e = tid; e < 8192; e += 256) {
        int t = e >> 7, m = e & 127;
        Kh[e] = (_Float16)fqkv[(long)(s0 + t) * 4096 + 1024 + hq * 128 + m];
        Qh[e] = (_Float16)fqkv[(long)(s0 + t) * 4096 + hq * 128 + m];
    }
    __syncthreads();
    if (tid < 64) bgam[hc * 64 + tid] = bet[tid] * expf(lg[tid]);
    if (tid == 0) gamC[hc] = expf(lg[63]);
    for (int e = tid; e < 8192; e += 256) {
        int t = e >> 7;
        QTw[(long)hc * 8192 + e] = (_Float16)(expf(lg[t]) * (float)Qh[e]);
    }
    for (int e = tid; e < 8192; e += 256) {
        int m = e >> 6, t = e & 63;
        KTw[(long)hc * 8192 + e] = (_Float16)(expf(lg[63] - lg[t]) * (float)Kh[t * 128 + m]);
    }
    const int wv = tid >> 6, lane = tid & 63, fr = lane & 15, kof = (lane >> 4) * 8, quad = lane >> 4;
    f32x4 accT[4], accM[4];
    f32x4 zero = {0.f, 0.f, 0.f, 0.f};
#pragma unroll
    for (int ci = 0; ci < 4; ci++) { accT[ci] = zero; accM[ci] = zero; }
    for (int k0 = 0; k0 < 128; k0 += 32) {
        f16x8 ak = *(const f16x8*)&Kh[(wv * 16 + fr) * 128 + k0 + kof];
        f16x8 aq = *(const f16x8*)&Qh[(wv * 16 + fr) * 128 + k0 + kof];
#pragma unroll
        for (int ci = 0; ci < 4; ci++) {
            f16x8 bk = *(const f16x8*)&Kh[(ci * 16 + fr) * 128 + k0 + kof];
            accT[ci] = MFMA16(ak, bk, accT[ci]);
            accM[ci] = MFMA16(aq, bk, accM[ci]);
        }
    }
#pragma unroll
    for (int ci = 0; ci < 4; ci++)
#pragma unroll
        for (int r = 0; r < 4; r++) {
            int t = wv * 16 + quad * 4 + r, i = ci * 16 + fr;
            float e = expf(lg[t] - lg[i]);
            Tw[(long)hc * 4096 + t * 64 + i] = (_Float16)((i < t) ? bet[t] * e * accT[ci][r] : 0.f);
            Mw[(long)hc * 4096 + t * 64 + i] = (_Float16)((i <= t) ? e * accM[ci][r] : 0.f);
        }
}

// ---------------------------------------------------------------- blocked forward substitution
__global__ __launch_bounds__(128) void solve_chunk(const float* __restrict__ fqkv,
                                                   const float* __restrict__ betaB,
                                                   const float* __restrict__ bgam,
                                                   const _Float16* __restrict__ Tw,
                                                   _Float16* __restrict__ WTw,
                                                   _Float16* __restrict__ Bw,
                                                   _Float16* __restrict__ BTw) {
    __shared__ float Tl[64 * 64];
    __shared__ float XD[64 * 128];
    const int bid = blockIdx.x;
    const int hc = bid >> 1, half = bid & 1;
    const int h = hc >> 4, c = hc & 15, hq = h >> 1, s0 = c * 64;
    const int j = threadIdx.x;
    for (int e = j; e < 4096; e += 128) Tl[e] = (float)Tw[(long)hc * 4096 + e];
    __syncthreads();
    float Xa[16];
    for (int a = 0; a < 4; ++a) {
#pragma unroll
        for (int r = 0; r < 16; ++r) {
            int t = a * 16 + r;
            float rv;
            if (half == 0)
                rv = betaB[(s0 + t) * 16 + h] * fqkv[(long)(s0 + t) * 4096 + 2048 + h * 128 + j];
            else
                rv = bgam[hc * 64 + t] * fqkv[(long)(s0 + t) * 4096 + 1024 + hq * 128 + j];
            Xa[r] = rv;
        }
        for (int b = 0; b < a; ++b) {
            float xk[16];
#pragma unroll
            for (int k = 0; k < 16; ++k) xk[k] = XD[(b * 16 + k) * 128 + j];
#pragma unroll
            for (int k = 0; k < 16; ++k)
#pragma unroll
                for (int r = 0; r < 16; ++r)
                    Xa[r] -= Tl[(a * 16 + r) * 64 + b * 16 + k] * xk[k];
        }
#pragma unroll
        for (int tp = 0; tp < 16; ++tp) {
            float xt = Xa[tp];
#pragma unroll
            for (int sp = 0; sp < 16; ++sp)
                if (sp > tp) Xa[sp] -= Tl[(a * 16 + sp) * 64 + a * 16 + tp] * xt;
        }
#pragma unroll
        for (int r = 0; r < 16; ++r) XD[(a * 16 + r) * 128 + j] = Xa[r];
    }
    __syncthreads();
    if (half == 0) {
        for (int t = 0; t < 64; ++t)
            WTw[((long)hc * 128 + j) * 64 + t] = (_Float16)XD[t * 128 + j];
    } else {
        for (int t = 0; t < 64; ++t) {
            _Float16 v = (_Float16)XD[t * 128 + j];
            Bw[(long)hc * 8192 + t * 128 + j] = v;
            BTw[((long)hc * 128 + j) * 64 + t] = v;
        }
    }
}

// ---------------------------------------------------------------- G = K~^T B (f16), Rt = (K~^T W)^T (f32)
__global__ __launch_bounds__(256) void gr_kernel(const _Float16* __restrict__ KTw,
                                                 const _Float16* __restrict__ BTw,
                                                 const _Float16* __restrict__ WTw,
                                                 _Float16* __restrict__ Gw,
                                                 float* __restrict__ Rtw) {
    __shared__ _Float16 KTl[128 * 72], BTl[128 * 72], WTl[128 * 72];
    const long hc = blockIdx.x;
    const int tid = threadIdx.x;
    {
        int r = tid >> 1, c0 = (tid & 1) * 32;
        const _Float16* k_ = &KTw[hc * 8192 + r * 64 + c0];
        const _Float16* b_ = &BTw[hc * 8192 + r * 64 + c0];
        const _Float16* w_ = &WTw[hc * 8192 + r * 64 + c0];
#pragma unroll
        for (int i = 0; i < 4; i++) {
            *(f16x8*)&KTl[r * 72 + c0 + i * 8] = *(const f16x8*)&k_[i * 8];
            *(f16x8*)&BTl[r * 72 + c0 + i * 8] = *(const f16x8*)&b_[i * 8];
            *(f16x8*)&WTl[r * 72 + c0 + i * 8] = *(const f16x8*)&w_[i * 8];
        }
    }
    __syncthreads();
    const int wv = tid >> 6, lane = tid & 63;
    const int fr = lane & 15, kof = (lane >> 4) * 8, quad = lane >> 4;
    f32x4 zero = {0.f, 0.f, 0.f, 0.f};
#pragma unroll
    for (int mi = 0; mi < 2; mi++) {
        int m0 = (wv * 2 + mi) * 16;
        f16x8 a0 = *(const f16x8*)&KTl[(m0 + fr) * 72 + kof];
        f16x8 a1 = *(const f16x8*)&KTl[(m0 + fr) * 72 + 32 + kof];
#pragma unroll
        for (int nj = 0; nj < 8; nj++) {
            f32x4 acc = zero;
            acc = MFMA16(a0, *(const f16x8*)&BTl[(nj * 16 + fr) * 72 + kof], acc);
            acc = MFMA16(a1, *(const f16x8*)&BTl[(nj * 16 + fr) * 72 + 32 + kof], acc);
#pragma unroll
            for (int r = 0; r < 4; r++)
                Gw[hc * 16384 + (long)(m0 + quad * 4 + r) * 128 + nj * 16 + fr] = (_Float16)acc[r];
        }
    }
#pragma unroll
    for (int ji = 0; ji < 2; ji++) {
        int j0 = (wv * 2 + ji) * 16;
        f16x8 a0 = *(const f16x8*)&WTl[(j0 + fr) * 72 + kof];
        f16x8 a1 = *(const f16x8*)&WTl[(j0 + fr) * 72 + 32 + kof];
#pragma unroll
        for (int nm = 0; nm < 8; nm++) {
            f32x4 acc = zero;
            acc = MFMA16(a0, *(const f16x8*)&KTl[(nm * 16 + fr) * 72 + kof], acc);
            acc = MFMA16(a1, *(const f16x8*)&KTl[(nm * 16 + fr) * 72 + 32 + kof], acc);
#pragma unroll
            for (int r = 0; r < 4; r++)
                Rtw[hc * 16384 + (long)(j0 + quad * 4 + r) * 128 + nm * 16 + fr] = acc[r];
        }
    }
}

// ---------------------------------------------------------------- serial affine state scan
__global__ __launch_bounds__(256) void serial_scan(const _Float16* __restrict__ Gw,
                                                   const float* __restrict__ Rtw,
                                                   const float* __restrict__ gamC,
                                                   float* __restrict__ Zdump) {
    __shared__ _Float16 Zhi[32 * 136], Zlo[32 * 136];
    __shared__ _Float16 Gl[128 * 136];
    const int tid = threadIdx.x;
    const int h = blockIdx.x >> 2, js = (blockIdx.x & 3) * 32;
    const int wv = tid >> 6, lane = tid & 63;
    const int fr = lane & 15, kof = (lane >> 4) * 8, quad = lane >> 4;
    const int gr_ = tid >> 1, gc_ = (tid & 1) * 64;

    for (int e = tid; e < 32 * 136; e += 256) { Zhi[e] = (_Float16)0.f; Zlo[e] = (_Float16)0.f; }
    float z[2][2][4];
#pragma unroll
    for (int jt = 0; jt < 2; jt++)
#pragma unroll
        for (int u = 0; u < 2; u++)
#pragma unroll
            for (int r = 0; r < 4; r++) z[jt][u][r] = 0.f;

    long hc0 = (long)h * 16;
    f16x8 gpre[8];
#pragma unroll
    for (int i = 0; i < 8; i++)
        gpre[i] = *(const f16x8*)&Gw[hc0 * 16384 + (long)gr_ * 128 + gc_ + i * 8];
    float rpre[2][2][4];
#pragma unroll
    for (int jt = 0; jt < 2; jt++)
#pragma unroll
        for (int u = 0; u < 2; u++)
#pragma unroll
            for (int r = 0; r < 4; r++)
                rpre[jt][u][r] = Rtw[hc0 * 16384 +
                                     (long)(js + jt * 16 + quad * 4 + r) * 128 +
                                     (2 * wv + u) * 16 + fr];
    __syncthreads();

    for (int c = 0; c < 16; ++c) {
        long hc = (long)h * 16 + c;
        float gC = gamC[hc];
#pragma unroll
        for (int i = 0; i < 8; i++)
            *(f16x8*)&Gl[gr_ * 136 + gc_ + i * 8] = gpre[i];
        long hcn = (long)h * 16 + (c < 15 ? c + 1 : 15);
        f16x8 gnext[8];
#pragma unroll
        for (int i = 0; i < 8; i++)
            gnext[i] = *(const f16x8*)&Gw[hcn * 16384 + (long)gr_ * 128 + gc_ + i * 8];
        float rnext[2][2][4];
#pragma unroll
        for (int jt = 0; jt < 2; jt++)
#pragma unroll
            for (int u = 0; u < 2; u++)
#pragma unroll
                for (int r = 0; r < 4; r++)
                    rnext[jt][u][r] = Rtw[hcn * 16384 +
                                          (long)(js + jt * 16 + quad * 4 + r) * 128 +
                                          (2 * wv + u) * 16 + fr];
        __syncthreads();
        f32x4 acc[2][2];
        f32x4 zero = {0.f, 0.f, 0.f, 0.f};
#pragma unroll
        for (int jt = 0; jt < 2; jt++)
#pragma unroll
            for (int u = 0; u < 2; u++) acc[jt][u] = zero;
        for (int k0 = 0; k0 < 128; k0 += 32) {
            f16x8 ahi[2], alo[2], bfr[2];
#pragma unroll
            for (int jt = 0; jt < 2; jt++) {
                ahi[jt] = *(const f16x8*)&Zhi[(jt * 16 + fr) * 136 + k0 + kof];
                alo[jt] = *(const f16x8*)&Zlo[(jt * 16 + fr) * 136 + k0 + kof];
            }
#pragma unroll
            for (int u = 0; u < 2; u++)
                bfr[u] = *(const f16x8*)&Gl[((2 * wv + u) * 16 + fr) * 136 + k0 + kof];
#pragma unroll
            for (int jt = 0; jt < 2; jt++)
#pragma unroll
                for (int u = 0; u < 2; u++) {
                    acc[jt][u] = MFMA16(ahi[jt], bfr[u], acc[jt][u]);
                    acc[jt][u] = MFMA16(alo[jt], bfr[u], acc[jt][u]);
                }
        }
        __syncthreads();
#pragma unroll
        for (int jt = 0; jt < 2; jt++)
#pragma unroll
            for (int u = 0; u < 2; u++)
#pragma unroll
                for (int r = 0; r < 4; r++) {
                    int j = jt * 16 + quad * 4 + r;
                    int m = (2 * wv + u) * 16 + fr;
                    Zdump[hc * 16384 + (long)(js + j) * 128 + m] = z[jt][u][r];
                    float zn = gC * z[jt][u][r] - acc[jt][u][r] + rpre[jt][u][r];
                    z[jt][u][r] = zn;
                    _Float16 hi = (_Float16)zn;
                    Zhi[j * 136 + m] = hi;
                    Zlo[j * 136 + m] = (_Float16)(zn - (float)hi);
                }
#pragma unroll
        for (int i = 0; i < 8; i++) gpre[i] = gnext[i];
#pragma unroll
        for (int jt = 0; jt < 2; jt++)
#pragma unroll
            for (int u = 0; u < 2; u++)
#pragma unroll
                for (int r = 0; r < 4; r++) rpre[jt][u][r] = rnext[jt][u][r];
    }
}

// ---------------------------------------------------------------- per-chunk output (parallel)
__global__ __launch_bounds__(256) void out_chunk(const float* __restrict__ Zdump,
                                                 const _Float16* __restrict__ Bw,
                                                 const _Float16* __restrict__ WTw,
                                                 const _Float16* __restrict__ QTw,
                                                 const _Float16* __restrict__ Mw,
                                                 float* __restrict__ ctx) {
    __shared__ _Float16 SThi[64 * 136], STlo[64 * 136], Bl[64 * 136];
    __shared__ _Float16 UT[64 * 72];
    const int bid = blockIdx.x;
    const long hc = bid >> 1;
    const int jh = (bid & 1) * 64;
    const int h = (int)(hc >> 4), c = (int)(hc & 15), s0 = c * 64;
    const int tid = threadIdx.x, wv = tid >> 6, lane = tid & 63;
    const int fr = lane & 15, kof = (lane >> 4) * 8, quad = lane >> 4;
    {
        int r = tid >> 2, c0 = (tid & 3) * 32;
        const float* src = &Zdump[hc * 16384 + (long)(jh + r) * 128 + c0];
#pragma unroll
        for (int i = 0; i < 8; i++) {
            float4 v = *(const float4*)&src[i * 4];
            _Float16 h0 = (_Float16)v.x, h1 = (_Float16)v.y, h2 = (_Float16)v.z, h3 = (_Float16)v.w;
            f16x4 hi = {h0, h1, h2, h3};
            f16x4 lo = {(_Float16)(v.x - (float)h0), (_Float16)(v.y - (float)h1),
                        (_Float16)(v.z - (float)h2), (_Float16)(v.w - (float)h3)};
            *(f16x4*)&SThi[r * 136 + c0 + i * 4] = hi;
            *(f16x4*)&STlo[r * 136 + c0 + i * 4] = lo;
        }
        const _Float16* bsrc = &Bw[hc * 8192 + r * 128 + c0];
#pragma unroll
        for (int i = 0; i < 4; i++)
            *(f16x8*)&Bl[r * 136 + c0 + i * 8] = *(const f16x8*)&bsrc[i * 8];
    }
    __syncthreads();
    const int t0 = wv * 16;
    f16x8 ba[4];
#pragma unroll
    for (int k = 0; k < 4; k++)
        ba[k] = *(const f16x8*)&Bl[(t0 + fr) * 136 + k * 32 + kof];
#pragma unroll
    for (int jt = 0; jt < 4; jt++) {
        f32x4 acc = {0.f, 0.f, 0.f, 0.f};
#pragma unroll
        for (int k = 0; k < 4; k++) {
            acc = MFMA16(ba[k], *(const f16x8*)&SThi[(jt * 16 + fr) * 136 + k * 32 + kof], acc);
            acc = MFMA16(ba[k], *(const f16x8*)&STlo[(jt * 16 + fr) * 136 + k * 32 + kof], acc);
        }
#pragma unroll
        for (int r = 0; r < 4; r++) {
            int t = t0 + quad * 4 + r;
            int j = jt * 16 + fr;
            float w = (float)WTw[hc * 8192 + (long)(jh + j) * 64 + t];
            UT[j * 72 + t] = (_Float16)(w - acc[r]);
        }
    }
    __syncthreads();
    f16x8 qa[4], ma[2];
#pragma unroll
    for (int k = 0; k < 4; k++)
        qa[k] = *(const f16x8*)&QTw[hc * 8192 + (long)(t0 + fr) * 128 + k * 32 + kof];
#pragma unroll
    for (int k = 0; k < 2; k++)
        ma[k] = *(const f16x8*)&Mw[hc * 4096 + (long)(t0 + fr) * 64 + k * 32 + kof];
#pragma unroll
    for (int jt = 0; jt < 4; jt++) {
        f32x4 acc = {0.f, 0.f, 0.f, 0.f};
#pragma unroll
        for (int k = 0; k < 4; k++) {
            acc = MFMA16(qa[k], *(const f16x8*)&SThi[(jt * 16 + fr) * 136 + k * 32 + kof], acc);
            acc = MFMA16(qa[k], *(const f16x8*)&STlo[(jt * 16 + fr) * 136 + k * 32 + kof], acc);
        }
#pragma unroll
        for (int k = 0; k < 2; k++)
            acc = MFMA16(ma[k], *(const f16x8*)&UT[(jt * 16 + fr) * 72 + k * 32 + kof], acc);
#pragma unroll
        for (int r = 0; r < 4; r++) {
            int t = t0 + quad * 4 + r;
            int j = jt * 16 + fr;
            ctx[(long)(s0 + t) * 2048 + h * 128 + jh + j] = acc[r];
        }
    }
}

// ---------------------------------------------------------------- rms_norm(ctx)*rms_w * silu(gate f16) -> f16
__global__ void epilogue_k(const float* __restrict__ ctx, const _Float16* __restrict__ pre,
                           const float* __restrict__ rms_w, _Float16* __restrict__ y) {
    int gw = (blockIdx.x * blockDim.x + threadIdx.x) >> 6;
    int lane = threadIdx.x & 63;
    int s = gw >> 4, h = gw & 15;
    long base = (long)s * 2048 + h * 128;
    long gbase = (long)s * 6144 + 4096 + h * 128;
    float2 cv = *(const float2*)&ctx[base + lane * 2];
    float ss = cv.x * cv.x + cv.y * cv.y;
#pragma unroll
    for (int m = 1; m < 64; m <<= 1) ss += __shfl_xor(ss, m);
    float sc = rsqrtf(ss * (1.f / 128.f) + 1e-6f);
    int d = lane * 2;
    float2 rw = *(const float2*)&rms_w[d];
    f16x2 gv = *(const f16x2*)&pre[gbase + d];
    float g0 = silu_f((float)gv[0]);
    float g1 = silu_f((float)gv[1]);
    f16x2 hv = { (_Float16)(cv.x * sc * rw.x * g0), (_Float16)(cv.y * sc * rw.y * g1) };
    *(f16x2*)&y[base + d] = hv;
}

// ---------------------------------------------------------------- launch
extern "C" void kernel_launch(void* const* d_in, const int* in_sizes, int n_in,
                              void* d_out, int out_size, void* d_ws, size_t ws_size,
                              hipStream_t stream) {
    const float* x       = (const float*)d_in[0];
    const float* w_qkv   = (const float*)d_in[1];
    const float* w_gate  = (const float*)d_in[2];
    const float* w_beta  = (const float*)d_in[3];
    const float* w_alpha = (const float*)d_in[4];
    const float* log_A   = (const float*)d_in[5];
    const float* dt_bias = (const float*)d_in[6];
    const float* conv_w  = (const float*)d_in[7];
    const float* rms_w   = (const float*)d_in[8];
    const float* w_out   = (const float*)d_in[9];
    float* outp = (float*)d_out;

    char* ws = (char*)d_ws;
    size_t off = 0;
    _Float16* xb     = (_Float16*)(ws + off); off += (size_t)1024 * 2048 * 2;   // | contiguous
    _Float16* wfused = (_Float16*)(ws + off); off += (size_t)6144 * 2048 * 2;   // | f16 cvt
    _Float16* woutb  = (_Float16*)(ws + off); off += (size_t)2048 * 2048 * 2;   // | region
    _Float16* yb     = (_Float16*)(ws + off); off += (size_t)1024 * 2048 * 2;
    _Float16* pre    = (_Float16*)(ws + off); off += (size_t)1024 * 6144 * 2;   // f16 now
    float* fqkv      = (float*)(ws + off);    off += (size_t)1024 * 4096 * 4;
    float* ctx       = (float*)(ws + off);    off += (size_t)1024 * 16 * 128 * 4;
    float* betaB     = (float*)(ws + off);    off += (size_t)1024 * 16 * 4;
    float* lalphaB   = (float*)(ws + off);    off += (size_t)1024 * 16 * 4;
    _Float16* Tw     = (_Float16*)(ws + off); off += (size_t)256 * 4096 * 2;
    _Float16* Mw     = (_Float16*)(ws + off); off += (size_t)256 * 4096 * 2;
    _Float16* QTw    = (_Float16*)(ws + off); off += (size_t)256 * 8192 * 2;
    _Float16* KTw    = (_Float16*)(ws + off); off += (size_t)256 * 8192 * 2;
    _Float16* WTw    = (_Float16*)(ws + off); off += (size_t)256 * 8192 * 2;
    _Float16* Bw     = (_Float16*)(ws + off); off += (size_t)256 * 8192 * 2;
    _Float16* BTw    = (_Float16*)(ws + off); off += (size_t)256 * 8192 * 2;
    float* bgam      = (float*)(ws + off);    off += (size_t)256 * 64 * 4;
    float* gamC      = (float*)(ws + off);    off += (size_t)256 * 4;
    _Float16* Gw     = (_Float16*)(ws + off); off += (size_t)256 * 16384 * 2;
    float* Rtw       = (float*)(ws + off);    off += (size_t)256 * 16384 * 4;
    // Zdump aliases fqkv: fqkv's last reader is solve_chunk; serial_scan
    // (producer of Zdump) runs strictly after it on the same stream.
    float* Zdump     = fqkv;

    // all f32->f16 conversions (dst = xb|wfused|woutb contiguous) + proj_ba, one launch
    cvt_proj<<<19456, 256, 0, stream>>>(x, w_qkv, w_gate, w_out, xb,
                                        w_beta, w_alpha, log_A, dt_bias, betaB, lalphaB);

    // fused qkv+gate projection: 64x128 tiles -> 768 blocks (3/CU even), f16 out
    gemm_bt64h<<<dim3(48, 16), 256, 0, stream>>>(xb, wfused, pre, 6144, 2048);
    conv_norm<<<1024, 256, 0, stream>>>(pre, conv_w, fqkv);

    prep_chunk<<<256, 256, 0, stream>>>(fqkv, betaB, lalphaB, Tw, Mw, QTw, KTw, bgam, gamC);
    solve_chunk<<<512, 128, 0, stream>>>(fqkv, betaB, bgam, Tw, WTw, Bw, BTw);
    gr_kernel<<<256, 256, 0, stream>>>(KTw, BTw, WTw, Gw, Rtw);
    serial_scan<<<64, 256, 0, stream>>>(Gw, Rtw, gamC, Zdump);
    out_chunk<<<512, 256, 0, stream>>>(Zdump, Bw, WTw, QTw, Mw, ctx);

    epilogue_k<<<4096, 256, 0, stream>>>(ctx, pre, rms_w, yb);
    // out projection: 64x128 tiles -> 256 blocks (1/CU even), f32 out
    gemm_bt64<<<dim3(16, 16), 256, 0, stream>>>(yb, woutb, outp, 2048, 2048);
}

// Round 9
// 318.461 us; speedup vs baseline: 1.2290x; 1.0626x over previous
//
#include <hip/hip_runtime.h>

#define AS1 __attribute__((address_space(1)))
#define AS3 __attribute__((address_space(3)))

typedef _Float16 f16x8 __attribute__((ext_vector_type(8)));
typedef _Float16 f16x4 __attribute__((ext_vector_type(4)));
typedef _Float16 f16x2 __attribute__((ext_vector_type(2)));
typedef float f32x4 __attribute__((ext_vector_type(4)));

#define MFMA16(a, b, c) __builtin_amdgcn_mfma_f32_16x16x32_f16((a), (b), (c), 0, 0, 0)

// ---------------------------------------------------------------- helpers
__device__ __forceinline__ float silu_f(float v) { return v / (1.f + expf(-v)); }

__device__ __forceinline__ void gload_lds16(const void* g, void* l) {
    __builtin_amdgcn_global_load_lds((AS1 void*)g, (AS3 void*)l, 16, 0, 0);
}

// ---------------------------------------------------------------- fused cvt + proj_ba
// blocks [0,18432): f32->f16 of x|w_qkv|w_gate|w_out into one contiguous region
// blocks [18432,19456): beta / log-alpha projections
__global__ __launch_bounds__(256) void cvt_proj(const float* __restrict__ x,
                                                const float* __restrict__ w_qkv,
                                                const float* __restrict__ w_gate,
                                                const float* __restrict__ w_out,
                                                _Float16* __restrict__ dst,
                                                const float* __restrict__ w_beta,
                                                const float* __restrict__ w_alpha,
                                                const float* __restrict__ log_A,
                                                const float* __restrict__ dt_bias,
                                                float* __restrict__ betaB,
                                                float* __restrict__ lalphaB) {
    __shared__ float xs[2048];
    const int bid = blockIdx.x, tid = threadIdx.x;
    if (bid < 18432) {
        long i = ((long)bid * 256 + tid) * 4;
        const float* src; long off;
        if (i < 2097152)       { src = x;      off = 0; }
        else if (i < 10485760) { src = w_qkv;  off = 2097152; }
        else if (i < 14680064) { src = w_gate; off = 10485760; }
        else                   { src = w_out;  off = 14680064; }
        float4 v = *(const float4*)&src[i - off];
        f16x4 h = { (_Float16)v.x, (_Float16)v.y, (_Float16)v.z, (_Float16)v.w };
        *(f16x4*)&dst[i] = h;
        return;
    }
    const int s = bid - 18432;
    *(float4*)&xs[tid * 8]     = *(const float4*)&x[(long)s * 2048 + tid * 8];
    *(float4*)&xs[tid * 8 + 4] = *(const float4*)&x[(long)s * 2048 + tid * 8 + 4];
    __syncthreads();
    const int o = tid >> 3, j = tid & 7;
    const float* w = (o < 16) ? &w_beta[(long)o * 2048] : &w_alpha[(long)(o - 16) * 2048];
    float p = 0.f;
#pragma unroll 4
    for (int i = 0; i < 64; i++) {
        int d = i * 32 + j * 4;
        float4 wv = *(const float4*)&w[d];
        p += xs[d] * wv.x + xs[d + 1] * wv.y + xs[d + 2] * wv.z + xs[d + 3] * wv.w;
    }
    p += __shfl_xor(p, 1); p += __shfl_xor(p, 2); p += __shfl_xor(p, 4);
    if (j == 0) {
        if (o < 16) {
            betaB[s * 16 + o] = 1.f / (1.f + expf(-p));
        } else {
            int h = o - 16;
            float t = p + dt_bias[h];
            float sp = (t > 20.f) ? t : log1pf(expf(t));
            lalphaB[s * 16 + h] = -expf(log_A[h]) * sp;
        }
    }
}

// ---------------------------------------------------------------- GEMM: C(f16) = A * B^T, 64x128 tile
__global__ __launch_bounds__(256) void gemm_bt64h(const _Float16* __restrict__ A,
                                                  const _Float16* __restrict__ B,
                                                  _Float16* __restrict__ C, int N, int K) {
    __shared__ _Float16 S[192 * 32];
    const int tid = threadIdx.x;
    const int rowA0 = blockIdx.y * 64, rowB0 = blockIdx.x * 128;
    const int lane = tid & 63;
    const int wv = tid >> 6;
    const int rw = (wv & 1) * 32, cw = (wv >> 1) * 64;
    const int fr = lane & 15, kof = (lane >> 4) * 8;

    const _Float16* gp[3];
#pragma unroll
    for (int i = 0; i < 3; i++) {
        int u = tid + 256 * i;
        int row = u >> 2, c0 = (u & 3) * 8;
        gp[i] = (row < 64) ? A + (long)(rowA0 + row) * K + c0
                           : B + (long)(rowB0 + row - 64) * K + c0;
    }

    f32x4 zero = {0.f, 0.f, 0.f, 0.f};
    f32x4 acc[2][4];
#pragma unroll
    for (int mi = 0; mi < 2; mi++)
#pragma unroll
        for (int ni = 0; ni < 4; ni++) acc[mi][ni] = zero;

    for (int k0 = 0; k0 < K; k0 += 32) {
        __syncthreads();
#pragma unroll
        for (int i = 0; i < 3; i++)
            gload_lds16(gp[i] + k0, &S[(tid + 256 * i) * 8]);
        __syncthreads();
        f16x8 af[2], bf[4];
#pragma unroll
        for (int mi = 0; mi < 2; mi++) af[mi] = *(const f16x8*)&S[(rw + mi * 16 + fr) * 32 + kof];
#pragma unroll
        for (int ni = 0; ni < 4; ni++) bf[ni] = *(const f16x8*)&S[(64 + cw + ni * 16 + fr) * 32 + kof];
#pragma unroll
        for (int mi = 0; mi < 2; mi++)
#pragma unroll
            for (int ni = 0; ni < 4; ni++)
                acc[mi][ni] = MFMA16(af[mi], bf[ni], acc[mi][ni]);
    }
    const int rbase = (lane >> 4) * 4;
#pragma unroll
    for (int mi = 0; mi < 2; mi++)
#pragma unroll
        for (int ni = 0; ni < 4; ni++) {
            int row = rowA0 + rw + mi * 16 + rbase;
            int col = rowB0 + cw + ni * 16 + fr;
#pragma unroll
            for (int r = 0; r < 4; r++)
                C[(long)(row + r) * N + col] = (_Float16)acc[mi][ni][r];
        }
}

// ---------------------------------------------------------------- GEMM: C(f32) = A * B^T, 64x64 tile
// Out-projection shape (1024x2048x2048) -> grid (32,16) = 512 blocks = 2/CU even.
__global__ __launch_bounds__(256) void gemm_bt6464(const _Float16* __restrict__ A,
                                                   const _Float16* __restrict__ B,
                                                   float* __restrict__ C, int N, int K) {
    __shared__ _Float16 S[128 * 32];   // rows 0..63 A, 64..127 B
    const int tid = threadIdx.x;
    const int rowA0 = blockIdx.y * 64, rowB0 = blockIdx.x * 64;
    const int lane = tid & 63;
    const int wv = tid >> 6;
    const int rw = (wv & 1) * 32, cwol = (wv >> 1) * 32;
    const int fr = lane & 15, kof = (lane >> 4) * 8;

    const _Float16* gp[2];
#pragma unroll
    for (int i = 0; i < 2; i++) {
        int u = tid + 256 * i;
        int row = u >> 2, c0 = (u & 3) * 8;
        gp[i] = (row < 64) ? A + (long)(rowA0 + row) * K + c0
                           : B + (long)(rowB0 + row - 64) * K + c0;
    }

    f32x4 zero = {0.f, 0.f, 0.f, 0.f};
    f32x4 acc[2][2];
#pragma unroll
    for (int mi = 0; mi < 2; mi++)
#pragma unroll
        for (int ni = 0; ni < 2; ni++) acc[mi][ni] = zero;

    for (int k0 = 0; k0 < K; k0 += 32) {
        __syncthreads();
#pragma unroll
        for (int i = 0; i < 2; i++)
            gload_lds16(gp[i] + k0, &S[(tid + 256 * i) * 8]);
        __syncthreads();
        f16x8 af[2], bf[2];
#pragma unroll
        for (int mi = 0; mi < 2; mi++) af[mi] = *(const f16x8*)&S[(rw + mi * 16 + fr) * 32 + kof];
#pragma unroll
        for (int ni = 0; ni < 2; ni++) bf[ni] = *(const f16x8*)&S[(64 + cwol + ni * 16 + fr) * 32 + kof];
#pragma unroll
        for (int mi = 0; mi < 2; mi++)
#pragma unroll
            for (int ni = 0; ni < 2; ni++)
                acc[mi][ni] = MFMA16(af[mi], bf[ni], acc[mi][ni]);
    }
    const int rbase = (lane >> 4) * 4;
#pragma unroll
    for (int mi = 0; mi < 2; mi++)
#pragma unroll
        for (int ni = 0; ni < 2; ni++) {
            int row = rowA0 + rw + mi * 16 + rbase;
            int col = rowB0 + cwol + ni * 16 + fr;
#pragma unroll
            for (int r = 0; r < 4; r++)
                C[(long)(row + r) * N + col] = acc[mi][ni][r];
        }
}

// ---------------------------------------------------------------- chunk front: conv+silu+l2norm
// + gamma cumsum + QT/KT/M/T + dual in-place forward substitution. One block per (head,chunk).
// Replaces conv_norm + prep_chunk + solve_chunk; fqkv and Tw never materialized.
__global__ __launch_bounds__(256) void chunk_front(const _Float16* __restrict__ pre,
                                                   const float* __restrict__ cw,
                                                   const float* __restrict__ betaB,
                                                   const float* __restrict__ lalphaB,
                                                   _Float16* __restrict__ Mw,
                                                   _Float16* __restrict__ QTw,
                                                   _Float16* __restrict__ KTw,
                                                   _Float16* __restrict__ WTw,
                                                   _Float16* __restrict__ Bw,
                                                   _Float16* __restrict__ BTw,
                                                   float* __restrict__ gamC) {
    __shared__ _Float16 Kh[64 * 128];   // becomes K-solve X in-place
    __shared__ _Float16 Qh[64 * 128];
    __shared__ _Float16 Vh[64 * 128];   // becomes V-solve X in-place
    __shared__ _Float16 Tl[64 * 64];
    __shared__ float lg[64], betL[64], bgamL[64];
    const int hc = blockIdx.x, h = hc >> 4, c = hc & 15, hq = h >> 1, s0 = c * 64;
    const int tid = threadIdx.x;

    if (tid < 64) {
        float la = lalphaB[(s0 + tid) * 16 + h];
#pragma unroll
        for (int d = 1; d < 64; d <<= 1) {
            float tv = __shfl_up(la, d, 64);
            if (tid >= d) la += tv;
        }
        lg[tid] = la;
        float b = betaB[(s0 + tid) * 16 + h];
        betL[tid] = b;
        bgamL[tid] = b * expf(la);
        if (tid == 63) gamC[hc] = expf(la);
    }

    // ---- causal conv(K=4)+SiLU (+l2 norm for q,k) -> LDS, f16
    {
        const int tt = tid >> 2, pp = tid & 3, m0 = pp * 32;
        const _Float16* rp[4];
        bool ok0, ok1, ok2;
        {
            int sb = s0 + tt - 3;
            ok0 = (sb >= 0); ok1 = (sb + 1 >= 0); ok2 = (sb + 2 >= 0);
            rp[0] = pre + (long)sb * 6144;
            rp[1] = pre + (long)(sb + 1) * 6144;
            rp[2] = pre + (long)(sb + 2) * 6144;
            rp[3] = pre + (long)(sb + 3) * 6144;
        }
#pragma unroll
        for (int sel = 0; sel < 3; sel++) {
            const int colbase = (sel == 0) ? hq * 128 : (sel == 1) ? 1024 + hq * 128
                                                                   : 2048 + h * 128;
            float vals[32];
            float ss = 0.f;
#pragma unroll
            for (int g = 0; g < 4; g++) {
                const int co = colbase + m0 + g * 8;
                f16x8 r0 = {}, r1 = {}, r2 = {}, r3;
                if (ok0) r0 = *(const f16x8*)&rp[0][co];
                if (ok1) r1 = *(const f16x8*)&rp[1][co];
                if (ok2) r2 = *(const f16x8*)&rp[2][co];
                r3 = *(const f16x8*)&rp[3][co];
#pragma unroll
                for (int j = 0; j < 8; j++) {
                    float4 w = *(const float4*)&cw[(co + j) * 4];
                    float a = (float)r0[j] * w.x + (float)r1[j] * w.y +
                              (float)r2[j] * w.z + (float)r3[j] * w.w;
                    a = silu_f(a);
                    vals[g * 8 + j] = a;
                    ss += a * a;
                }
            }
            float sc = 1.f;
            if (sel < 2) {
                ss += __shfl_xor(ss, 1); ss += __shfl_xor(ss, 2);  // 4-lane group (aligned)
                sc = rsqrtf(ss + 1e-6f);
                if (sel == 0) sc *= 0.08838834764831843f;  // 1/sqrt(128), queries
            }
            _Float16* dst = (sel == 0) ? Qh : (sel == 1) ? Kh : Vh;
#pragma unroll
            for (int g = 0; g < 4; g++) {
                f16x8 hv;
#pragma unroll
                for (int j = 0; j < 8; j++) hv[j] = (_Float16)(vals[g * 8 + j] * sc);
                *(f16x8*)&dst[tt * 128 + m0 + g * 8] = hv;
            }
        }
    }
    __syncthreads();

    // ---- scaled QT / KT global writes
    for (int e = tid; e < 8192; e += 256) {
        int t = e >> 7;
        QTw[(long)hc * 8192 + e] = (_Float16)(expf(lg[t]) * (float)Qh[e]);
    }
    {
        float lg63 = lg[63];
        for (int e = tid; e < 8192; e += 256) {
            int m = e >> 6, t = e & 63;
            KTw[(long)hc * 8192 + e] = (_Float16)(expf(lg63 - lg[t]) * (float)Kh[t * 128 + m]);
        }
    }

    // ---- T (LDS) and M (global) via MFMA
    const int wv = tid >> 6, lane = tid & 63, fr = lane & 15, kof = (lane >> 4) * 8, quad = lane >> 4;
    {
        f32x4 accT[4], accM[4];
        f32x4 zero = {0.f, 0.f, 0.f, 0.f};
#pragma unroll
        for (int ci = 0; ci < 4; ci++) { accT[ci] = zero; accM[ci] = zero; }
        for (int k0 = 0; k0 < 128; k0 += 32) {
            f16x8 ak = *(const f16x8*)&Kh[(wv * 16 + fr) * 128 + k0 + kof];
            f16x8 aq = *(const f16x8*)&Qh[(wv * 16 + fr) * 128 + k0 + kof];
#pragma unroll
            for (int ci = 0; ci < 4; ci++) {
                f16x8 bk = *(const f16x8*)&Kh[(ci * 16 + fr) * 128 + k0 + kof];
                accT[ci] = MFMA16(ak, bk, accT[ci]);
                accM[ci] = MFMA16(aq, bk, accM[ci]);
            }
        }
#pragma unroll
        for (int ci = 0; ci < 4; ci++)
#pragma unroll
            for (int r = 0; r < 4; r++) {
                int t = wv * 16 + quad * 4 + r, i = ci * 16 + fr;
                float e = expf(lg[t] - lg[i]);
                Tl[t * 64 + i] = (_Float16)((i < t) ? betL[t] * e * accT[ci][r] : 0.f);
                Mw[(long)hc * 4096 + t * 64 + i] = (_Float16)((i <= t) ? e * accM[ci][r] : 0.f);
            }
    }
    __syncthreads();

    // ---- dual concurrent forward substitution, in place.
    // threads 0..127: solve (I+T)X = diag(beta)V   (X in Vh)  -> WTw
    // threads 128..255: solve (I+T)X = diag(beta*gamma)K (X in Kh) -> Bw, BTw
    {
        const int jcol = tid & 127;
        const int halfsel = tid >> 7;
        _Float16* X = halfsel ? Kh : Vh;
        const float* dscale = halfsel ? bgamL : betL;
        float Xa[16];
        for (int a = 0; a < 4; ++a) {
#pragma unroll
            for (int r = 0; r < 16; ++r) {
                int t = a * 16 + r;
                Xa[r] = dscale[t] * (float)X[t * 128 + jcol];
            }
            for (int b = 0; b < a; ++b) {
                float xk[16];
#pragma unroll
                for (int k = 0; k < 16; ++k) xk[k] = (float)X[(b * 16 + k) * 128 + jcol];
#pragma unroll
                for (int k = 0; k < 16; ++k)
#pragma unroll
                    for (int r = 0; r < 16; ++r)
                        Xa[r] -= (float)Tl[(a * 16 + r) * 64 + b * 16 + k] * xk[k];
            }
#pragma unroll
            for (int tp = 0; tp < 16; ++tp) {
                float xt = Xa[tp];
#pragma unroll
                for (int sp = 0; sp < 16; ++sp)
                    if (sp > tp) Xa[sp] -= (float)Tl[(a * 16 + sp) * 64 + a * 16 + tp] * xt;
            }
#pragma unroll
            for (int r = 0; r < 16; ++r) X[(a * 16 + r) * 128 + jcol] = (_Float16)Xa[r];
        }
        if (halfsel == 0) {
            for (int t = 0; t < 64; ++t)
                WTw[((long)hc * 128 + jcol) * 64 + t] = Vh[t * 128 + jcol];
        } else {
            for (int t = 0; t < 64; ++t) {
                _Float16 v = Kh[t * 128 + jcol];
                Bw[(long)hc * 8192 + t * 128 + jcol] = v;
                BTw[((long)hc * 128 + jcol) * 64 + t] = v;
            }
        }
    }
}

// ---------------------------------------------------------------- G = K~^T B (f16), Rt = (K~^T W)^T (f32)
__global__ __launch_bounds__(256) void gr_kernel(const _Float16* __restrict__ KTw,
                                                 const _Float16* __restrict__ BTw,
                                                 const _Float16* __restrict__ WTw,
                                                 _Float16* __restrict__ Gw,
                                                 float* __restrict__ Rtw) {
    __shared__ _Float16 KTl[128 * 72], BTl[128 * 72], WTl[128 * 72];
    const long hc = blockIdx.x;
    const int tid = threadIdx.x;
    {
        int r = tid >> 1, c0 = (tid & 1) * 32;
        const _Float16* k_ = &KTw[hc * 8192 + r * 64 + c0];
        const _Float16* b_ = &BTw[hc * 8192 + r * 64 + c0];
        const _Float16* w_ = &WTw[hc * 8192 + r * 64 + c0];
#pragma unroll
        for (int i = 0; i < 4; i++) {
            *(f16x8*)&KTl[r * 72 + c0 + i * 8] = *(const f16x8*)&k_[i * 8];
            *(f16x8*)&BTl[r * 72 + c0 + i * 8] = *(const f16x8*)&b_[i * 8];
            *(f16x8*)&WTl[r * 72 + c0 + i * 8] = *(const f16x8*)&w_[i * 8];
        }
    }
    __syncthreads();
    const int wv = tid >> 6, lane = tid & 63;
    const int fr = lane & 15, kof = (lane >> 4) * 8, quad = lane >> 4;
    f32x4 zero = {0.f, 0.f, 0.f, 0.f};
#pragma unroll
    for (int mi = 0; mi < 2; mi++) {
        int m0 = (wv * 2 + mi) * 16;
        f16x8 a0 = *(const f16x8*)&KTl[(m0 + fr) * 72 + kof];
        f16x8 a1 = *(const f16x8*)&KTl[(m0 + fr) * 72 + 32 + kof];
#pragma unroll
        for (int nj = 0; nj < 8; nj++) {
            f32x4 acc = zero;
            acc = MFMA16(a0, *(const f16x8*)&BTl[(nj * 16 + fr) * 72 + kof], acc);
            acc = MFMA16(a1, *(const f16x8*)&BTl[(nj * 16 + fr) * 72 + 32 + kof], acc);
#pragma unroll
            for (int r = 0; r < 4; r++)
                Gw[hc * 16384 + (long)(m0 + quad * 4 + r) * 128 + nj * 16 + fr] = (_Float16)acc[r];
        }
    }
#pragma unroll
    for (int ji = 0; ji < 2; ji++) {
        int j0 = (wv * 2 + ji) * 16;
        f16x8 a0 = *(const f16x8*)&WTl[(j0 + fr) * 72 + kof];
        f16x8 a1 = *(const f16x8*)&WTl[(j0 + fr) * 72 + 32 + kof];
#pragma unroll
        for (int nm = 0; nm < 8; nm++) {
            f32x4 acc = zero;
            acc = MFMA16(a0, *(const f16x8*)&KTl[(nm * 16 + fr) * 72 + kof], acc);
            acc = MFMA16(a1, *(const f16x8*)&KTl[(nm * 16 + fr) * 72 + 32 + kof], acc);
#pragma unroll
            for (int r = 0; r < 4; r++)
                Rtw[hc * 16384 + (long)(j0 + quad * 4 + r) * 128 + nm * 16 + fr] = acc[r];
        }
    }
}

// ---------------------------------------------------------------- serial affine state scan
__global__ __launch_bounds__(256) void serial_scan(const _Float16* __restrict__ Gw,
                                                   const float* __restrict__ Rtw,
                                                   const float* __restrict__ gamC,
                                                   float* __restrict__ Zdump) {
    __shared__ _Float16 Zhi[32 * 136], Zlo[32 * 136];
    __shared__ _Float16 Gl[128 * 136];
    const int tid = threadIdx.x;
    const int h = blockIdx.x >> 2, js = (blockIdx.x & 3) * 32;
    const int wv = tid >> 6, lane = tid & 63;
    const int fr = lane & 15, kof = (lane >> 4) * 8, quad = lane >> 4;
    const int gr_ = tid >> 1, gc_ = (tid & 1) * 64;

    for (int e = tid; e < 32 * 136; e += 256) { Zhi[e] = (_Float16)0.f; Zlo[e] = (_Float16)0.f; }
    float z[2][2][4];
#pragma unroll
    for (int jt = 0; jt < 2; jt++)
#pragma unroll
        for (int u = 0; u < 2; u++)
#pragma unroll
            for (int r = 0; r < 4; r++) z[jt][u][r] = 0.f;

    long hc0 = (long)h * 16;
    f16x8 gpre[8];
#pragma unroll
    for (int i = 0; i < 8; i++)
        gpre[i] = *(const f16x8*)&Gw[hc0 * 16384 + (long)gr_ * 128 + gc_ + i * 8];
    float rpre[2][2][4];
#pragma unroll
    for (int jt = 0; jt < 2; jt++)
#pragma unroll
        for (int u = 0; u < 2; u++)
#pragma unroll
            for (int r = 0; r < 4; r++)
                rpre[jt][u][r] = Rtw[hc0 * 16384 +
                                     (long)(js + jt * 16 + quad * 4 + r) * 128 +
                                     (2 * wv + u) * 16 + fr];
    __syncthreads();

    for (int c = 0; c < 16; ++c) {
        long hc = (long)h * 16 + c;
        float gC = gamC[hc];
#pragma unroll
        for (int i = 0; i < 8; i++)
            *(f16x8*)&Gl[gr_ * 136 + gc_ + i * 8] = gpre[i];
        long hcn = (long)h * 16 + (c < 15 ? c + 1 : 15);
        f16x8 gnext[8];
#pragma unroll
        for (int i = 0; i < 8; i++)
            gnext[i] = *(const f16x8*)&Gw[hcn * 16384 + (long)gr_ * 128 + gc_ + i * 8];
        float rnext[2][2][4];
#pragma unroll
        for (int jt = 0; jt < 2; jt++)
#pragma unroll
            for (int u = 0; u < 2; u++)
#pragma unroll
                for (int r = 0; r < 4; r++)
                    rnext[jt][u][r] = Rtw[hcn * 16384 +
                                          (long)(js + jt * 16 + quad * 4 + r) * 128 +
                                          (2 * wv + u) * 16 + fr];
        __syncthreads();
        f32x4 acc[2][2];
        f32x4 zero = {0.f, 0.f, 0.f, 0.f};
#pragma unroll
        for (int jt = 0; jt < 2; jt++)
#pragma unroll
            for (int u = 0; u < 2; u++) acc[jt][u] = zero;
        for (int k0 = 0; k0 < 128; k0 += 32) {
            f16x8 ahi[2], alo[2], bfr[2];
#pragma unroll
            for (int jt = 0; jt < 2; jt++) {
                ahi[jt] = *(const f16x8*)&Zhi[(jt * 16 + fr) * 136 + k0 + kof];
                alo[jt] = *(const f16x8*)&Zlo[(jt * 16 + fr) * 136 + k0 + kof];
            }
#pragma unroll
            for (int u = 0; u < 2; u++)
                bfr[u] = *(const f16x8*)&Gl[((2 * wv + u) * 16 + fr) * 136 + k0 + kof];
#pragma unroll
            for (int jt = 0; jt < 2; jt++)
#pragma unroll
                for (int u = 0; u < 2; u++) {
                    acc[jt][u] = MFMA16(ahi[jt], bfr[u], acc[jt][u]);
                    acc[jt][u] = MFMA16(alo[jt], bfr[u], acc[jt][u]);
                }
        }
        __syncthreads();
#pragma unroll
        for (int jt = 0; jt < 2; jt++)
#pragma unroll
            for (int u = 0; u < 2; u++)
#pragma unroll
                for (int r = 0; r < 4; r++) {
                    int j = jt * 16 + quad * 4 + r;
                    int m = (2 * wv + u) * 16 + fr;
                    Zdump[hc * 16384 + (long)(js + j) * 128 + m] = z[jt][u][r];
                    float zn = gC * z[jt][u][r] - acc[jt][u][r] + rpre[jt][u][r];
                    z[jt][u][r] = zn;
                    _Float16 hi = (_Float16)zn;
                    Zhi[j * 136 + m] = hi;
                    Zlo[j * 136 + m] = (_Float16)(zn - (float)hi);
                }
#pragma unroll
        for (int i = 0; i < 8; i++) gpre[i] = gnext[i];
#pragma unroll
        for (int jt = 0; jt < 2; jt++)
#pragma unroll
            for (int u = 0; u < 2; u++)
#pragma unroll
                for (int r = 0; r < 4; r++) rpre[jt][u][r] = rnext[jt][u][r];
    }
}

// ---------------------------------------------------------------- per-chunk output (parallel)
__global__ __launch_bounds__(256) void out_chunk(const float* __restrict__ Zdump,
                                                 const _Float16* __restrict__ Bw,
                                                 const _Float16* __restrict__ WTw,
                                                 const _Float16* __restrict__ QTw,
                                                 const _Float16* __restrict__ Mw,
                                                 float* __restrict__ ctx) {
    __shared__ _Float16 SThi[64 * 136], STlo[64 * 136], Bl[64 * 136];
    __shared__ _Float16 UT[64 * 72];
    const int bid = blockIdx.x;
    const long hc = bid >> 1;
    const int jh = (bid & 1) * 64;
    const int h = (int)(hc >> 4), c = (int)(hc & 15), s0 = c * 64;
    const int tid = threadIdx.x, wv = tid >> 6, lane = tid & 63;
    const int fr = lane & 15, kof = (lane >> 4) * 8, quad = lane >> 4;
    {
        int r = tid >> 2, c0 = (tid & 3) * 32;
        const float* src = &Zdump[hc * 16384 + (long)(jh + r) * 128 + c0];
#pragma unroll
        for (int i = 0; i < 8; i++) {
            float4 v = *(const float4*)&src[i * 4];
            _Float16 h0 = (_Float16)v.x, h1 = (_Float16)v.y, h2 = (_Float16)v.z, h3 = (_Float16)v.w;
            f16x4 hi = {h0, h1, h2, h3};
            f16x4 lo = {(_Float16)(v.x - (float)h0), (_Float16)(v.y - (float)h1),
                        (_Float16)(v.z - (float)h2), (_Float16)(v.w - (float)h3)};
            *(f16x4*)&SThi[r * 136 + c0 + i * 4] = hi;
            *(f16x4*)&STlo[r * 136 + c0 + i * 4] = lo;
        }
        const _Float16* bsrc = &Bw[hc * 8192 + r * 128 + c0];
#pragma unroll
        for (int i = 0; i < 4; i++)
            *(f16x8*)&Bl[r * 136 + c0 + i * 8] = *(const f16x8*)&bsrc[i * 8];
    }
    __syncthreads();
    const int t0 = wv * 16;
    f16x8 ba[4];
#pragma unroll
    for (int k = 0; k < 4; k++)
        ba[k] = *(const f16x8*)&Bl[(t0 + fr) * 136 + k * 32 + kof];
#pragma unroll
    for (int jt = 0; jt < 4; jt++) {
        f32x4 acc = {0.f, 0.f, 0.f, 0.f};
#pragma unroll
        for (int k = 0; k < 4; k++) {
            acc = MFMA16(ba[k], *(const f16x8*)&SThi[(jt * 16 + fr) * 136 + k * 32 + kof], acc);
            acc = MFMA16(ba[k], *(const f16x8*)&STlo[(jt * 16 + fr) * 136 + k * 32 + kof], acc);
        }
#pragma unroll
        for (int r = 0; r < 4; r++) {
            int t = t0 + quad * 4 + r;
            int j = jt * 16 + fr;
            float w = (float)WTw[hc * 8192 + (long)(jh + j) * 64 + t];
            UT[j * 72 + t] = (_Float16)(w - acc[r]);
        }
    }
    __syncthreads();
    f16x8 qa[4], ma[2];
#pragma unroll
    for (int k = 0; k < 4; k++)
        qa[k] = *(const f16x8*)&QTw[hc * 8192 + (long)(t0 + fr) * 128 + k * 32 + kof];
#pragma unroll
    for (int k = 0; k < 2; k++)
        ma[k] = *(const f16x8*)&Mw[hc * 4096 + (long)(t0 + fr) * 64 + k * 32 + kof];
#pragma unroll
    for (int jt = 0; jt < 4; jt++) {
        f32x4 acc = {0.f, 0.f, 0.f, 0.f};
#pragma unroll
        for (int k = 0; k < 4; k++) {
            acc = MFMA16(qa[k], *(const f16x8*)&SThi[(jt * 16 + fr) * 136 + k * 32 + kof], acc);
            acc = MFMA16(qa[k], *(const f16x8*)&STlo[(jt * 16 + fr) * 136 + k * 32 + kof], acc);
        }
#pragma unroll
        for (int k = 0; k < 2; k++)
            acc = MFMA16(ma[k], *(const f16x8*)&UT[(jt * 16 + fr) * 72 + k * 32 + kof], acc);
#pragma unroll
        for (int r = 0; r < 4; r++) {
            int t = t0 + quad * 4 + r;
            int j = jt * 16 + fr;
            ctx[(long)(s0 + t) * 2048 + h * 128 + jh + j] = acc[r];
        }
    }
}

// ---------------------------------------------------------------- rms_norm(ctx)*rms_w * silu(gate f16) -> f16
__global__ void epilogue_k(const float* __restrict__ ctx, const _Float16* __restrict__ pre,
                           const float* __restrict__ rms_w, _Float16* __restrict__ y) {
    int gw = (blockIdx.x * blockDim.x + threadIdx.x) >> 6;
    int lane = threadIdx.x & 63;
    int s = gw >> 4, h = gw & 15;
    long base = (long)s * 2048 + h * 128;
    long gbase = (long)s * 6144 + 4096 + h * 128;
    float2 cv = *(const float2*)&ctx[base + lane * 2];
    float ss = cv.x * cv.x + cv.y * cv.y;
#pragma unroll
    for (int m = 1; m < 64; m <<= 1) ss += __shfl_xor(ss, m);
    float sc = rsqrtf(ss * (1.f / 128.f) + 1e-6f);
    int d = lane * 2;
    float2 rw = *(const float2*)&rms_w[d];
    f16x2 gv = *(const f16x2*)&pre[gbase + d];
    float g0 = silu_f((float)gv[0]);
    float g1 = silu_f((float)gv[1]);
    f16x2 hv = { (_Float16)(cv.x * sc * rw.x * g0), (_Float16)(cv.y * sc * rw.y * g1) };
    *(f16x2*)&y[base + d] = hv;
}

// ---------------------------------------------------------------- launch
extern "C" void kernel_launch(void* const* d_in, const int* in_sizes, int n_in,
                              void* d_out, int out_size, void* d_ws, size_t ws_size,
                              hipStream_t stream) {
    const float* x       = (const float*)d_in[0];
    const float* w_qkv   = (const float*)d_in[1];
    const float* w_gate  = (const float*)d_in[2];
    const float* w_beta  = (const float*)d_in[3];
    const float* w_alpha = (const float*)d_in[4];
    const float* log_A   = (const float*)d_in[5];
    const float* dt_bias = (const float*)d_in[6];
    const float* conv_w  = (const float*)d_in[7];
    const float* rms_w   = (const float*)d_in[8];
    const float* w_out   = (const float*)d_in[9];
    float* outp = (float*)d_out;

    char* ws = (char*)d_ws;
    size_t off = 0;
    _Float16* xb     = (_Float16*)(ws + off); off += (size_t)1024 * 2048 * 2;   // | contiguous
    _Float16* wfused = (_Float16*)(ws + off); off += (size_t)6144 * 2048 * 2;   // | f16 cvt
    _Float16* woutb  = (_Float16*)(ws + off); off += (size_t)2048 * 2048 * 2;   // | region
    _Float16* yb     = (_Float16*)(ws + off); off += (size_t)1024 * 2048 * 2;
    _Float16* pre    = (_Float16*)(ws + off); off += (size_t)1024 * 6144 * 2;
    float* ctx       = (float*)(ws + off);    off += (size_t)1024 * 16 * 128 * 4;
    float* betaB     = (float*)(ws + off);    off += (size_t)1024 * 16 * 4;
    float* lalphaB   = (float*)(ws + off);    off += (size_t)1024 * 16 * 4;
    _Float16* Mw     = (_Float16*)(ws + off); off += (size_t)256 * 4096 * 2;
    _Float16* QTw    = (_Float16*)(ws + off); off += (size_t)256 * 8192 * 2;
    _Float16* KTw    = (_Float16*)(ws + off); off += (size_t)256 * 8192 * 2;
    _Float16* WTw    = (_Float16*)(ws + off); off += (size_t)256 * 8192 * 2;
    _Float16* Bw     = (_Float16*)(ws + off); off += (size_t)256 * 8192 * 2;
    _Float16* BTw    = (_Float16*)(ws + off); off += (size_t)256 * 8192 * 2;
    float* gamC      = (float*)(ws + off);    off += (size_t)256 * 4;
    _Float16* Gw     = (_Float16*)(ws + off); off += (size_t)256 * 16384 * 2;
    float* Rtw       = (float*)(ws + off);    off += (size_t)256 * 16384 * 4;
    float* Zdump     = (float*)(ws + off);    off += (size_t)256 * 16384 * 4;

    // all f32->f16 conversions + beta/alpha projections, one launch
    cvt_proj<<<19456, 256, 0, stream>>>(x, w_qkv, w_gate, w_out, xb,
                                        w_beta, w_alpha, log_A, dt_bias, betaB, lalphaB);

    // fused qkv+gate projection: 64x128 tiles -> 768 blocks (3/CU even), f16 out
    gemm_bt64h<<<dim3(48, 16), 256, 0, stream>>>(xb, wfused, pre, 6144, 2048);

    // conv+norm+prep+solve fused: one block per (head,chunk)
    chunk_front<<<256, 256, 0, stream>>>(pre, conv_w, betaB, lalphaB,
                                         Mw, QTw, KTw, WTw, Bw, BTw, gamC);
    gr_kernel<<<256, 256, 0, stream>>>(KTw, BTw, WTw, Gw, Rtw);
    serial_scan<<<64, 256, 0, stream>>>(Gw, Rtw, gamC, Zdump);
    out_chunk<<<512, 256, 0, stream>>>(Zdump, Bw, WTw, QTw, Mw, ctx);

    epilogue_k<<<4096, 256, 0, stream>>>(ctx, pre, rms_w, yb);
    // out projection: 64x64 tiles -> 512 blocks (2/CU even)
    gemm_bt6464<<<dim3(32, 16), 256, 0, stream>>>(yb, woutb, outp, 2048, 2048);
}